// Round 1
// baseline (7018.139 us; speedup 1.0000x reference)
//
#include <hip/hip_runtime.h>
#include <math.h>

#define DD 256
#define DFFN 1024
#define LQT 12240
#define BB 2
#define MROWS (BB * LQT)   // 24480

__device__ __forceinline__ void level_of(int q, int& lvl, int& start, int& S) {
    if (q < 9216)       { lvl = 0; start = 0;     S = 96; }
    else if (q < 11520) { lvl = 1; start = 9216;  S = 48; }
    else if (q < 12096) { lvl = 2; start = 11520; S = 24; }
    else                { lvl = 3; start = 12096; S = 12; }
}

// ---------------------------------------------------------------------------
// Generic tiled fp32 GEMM: C[M,N] = op(A[M,K] @ W[N,K]^T + bias[N] (+R))
// op: 0=none, 1=relu, 2=+residual R
// transA: A[m,k] = A[k*M + m]  (used for input projections from (Cin,HW))
// grid.z batches with strides aZ/rZ/cZ.
// ---------------------------------------------------------------------------
__global__ __launch_bounds__(256)
void gemm_tiled(const float* __restrict__ A, long aZ, int transA,
                const float* __restrict__ W, const float* __restrict__ bias,
                const float* __restrict__ R, long rZ,
                float* __restrict__ C, long cZ,
                int M, int N, int K, int op)
{
    __shared__ float As[16][68];
    __shared__ float Bs[16][68];
    const int z = blockIdx.z;
    A += (long)z * aZ;
    C += (long)z * cZ;
    const float* Rz = R ? (R + (long)z * rZ) : nullptr;
    const int m0 = blockIdx.x * 64;
    const int n0 = blockIdx.y * 64;
    const int t = threadIdx.x;
    const int tx = t & 15, ty = t >> 4;
    float acc[4][4] = {};

    for (int k0 = 0; k0 < K; k0 += 16) {
        if (transA) {
            const int kk = t & 15, mm = (t >> 4) << 2;
            const int gm = m0 + mm;
            float4 v = make_float4(0.f, 0.f, 0.f, 0.f);
            if (gm + 3 < M) {
                v = *(const float4*)(A + (long)(k0 + kk) * M + gm);
            } else if (gm < M) {
                const float* p = A + (long)(k0 + kk) * M;
                v.x = p[gm];
                if (gm + 1 < M) v.y = p[gm + 1];
                if (gm + 2 < M) v.z = p[gm + 2];
            }
            *(float4*)&As[kk][mm] = v;
        } else {
            const int mm = t >> 2, kq = (t & 3) << 2;
            const int gm = m0 + mm;
            float4 v = make_float4(0.f, 0.f, 0.f, 0.f);
            if (gm < M) v = *(const float4*)(A + (long)gm * K + k0 + kq);
            As[kq + 0][mm] = v.x; As[kq + 1][mm] = v.y;
            As[kq + 2][mm] = v.z; As[kq + 3][mm] = v.w;
        }
        {
            const int nn = t >> 2, kq = (t & 3) << 2;
            float4 v = *(const float4*)(W + (long)(n0 + nn) * K + k0 + kq);
            Bs[kq + 0][nn] = v.x; Bs[kq + 1][nn] = v.y;
            Bs[kq + 2][nn] = v.z; Bs[kq + 3][nn] = v.w;
        }
        __syncthreads();
        #pragma unroll
        for (int k = 0; k < 16; ++k) {
            const float4 a4 = *(const float4*)&As[k][ty << 2];
            const float4 b4 = *(const float4*)&Bs[k][tx << 2];
            const float av[4] = {a4.x, a4.y, a4.z, a4.w};
            const float bv[4] = {b4.x, b4.y, b4.z, b4.w};
            #pragma unroll
            for (int i = 0; i < 4; ++i)
                #pragma unroll
                for (int j = 0; j < 4; ++j)
                    acc[i][j] = fmaf(av[i], bv[j], acc[i][j]);
        }
        __syncthreads();
    }

    #pragma unroll
    for (int i = 0; i < 4; ++i) {
        const int gm = m0 + (ty << 2) + i;
        if (gm >= M) continue;
        #pragma unroll
        for (int j = 0; j < 4; ++j) {
            const int gn = n0 + (tx << 2) + j;
            float v = acc[i][j] + bias[gn];
            if (op == 1) v = fmaxf(v, 0.f);
            else if (op == 2) v += Rz[(long)gm * N + gn];
            C[(long)gm * N + gn] = v;
        }
    }
}

// ---------------------------------------------------------------------------
// GroupNorm over (level tokens x 8 channels) per (batch, level, group)
// ---------------------------------------------------------------------------
__global__ __launch_bounds__(256)
void groupnorm_k(float* __restrict__ src, const float* __restrict__ gg,
                 const float* __restrict__ gb)
{
    const int grp = blockIdx.x;   // 0..31
    const int lvl = blockIdx.y;   // 0..3
    const int b   = blockIdx.z;   // 0..B-1
    const int sizes[4]  = {9216, 2304, 576, 144};
    const int starts[4] = {0, 9216, 11520, 12096};
    const int Ml = sizes[lvl];
    float* base = src + ((long)b * LQT + starts[lvl]) * DD + grp * 8;
    const int t = threadIdx.x;
    float sum = 0.f, ssq = 0.f;
    for (int r = t; r < Ml; r += 256) {
        const float* p = base + (long)r * DD;
        float4 v0 = *(const float4*)p;
        float4 v1 = *(const float4*)(p + 4);
        sum += (v0.x + v0.y) + (v0.z + v0.w) + (v1.x + v1.y) + (v1.z + v1.w);
        ssq += v0.x * v0.x + v0.y * v0.y + v0.z * v0.z + v0.w * v0.w
             + v1.x * v1.x + v1.y * v1.y + v1.z * v1.z + v1.w * v1.w;
    }
    #pragma unroll
    for (int o = 32; o > 0; o >>= 1) {
        sum += __shfl_down(sum, o);
        ssq += __shfl_down(ssq, o);
    }
    __shared__ float sh[8];
    if ((t & 63) == 0) { sh[t >> 6] = sum; sh[4 + (t >> 6)] = ssq; }
    __syncthreads();
    const float tot = sh[0] + sh[1] + sh[2] + sh[3];
    const float tq  = sh[4] + sh[5] + sh[6] + sh[7];
    const float cnt = (float)(Ml * 8);
    const float mean = tot / cnt;
    const float inv = rsqrtf(tq / cnt - mean * mean + 1e-5f);
    float g0[8], b0[8];
    #pragma unroll
    for (int c = 0; c < 8; ++c) {
        g0[c] = gg[lvl * DD + grp * 8 + c];
        b0[c] = gb[lvl * DD + grp * 8 + c];
    }
    for (int r = t; r < Ml; r += 256) {
        float* p = base + (long)r * DD;
        float4 v0 = *(float4*)p;
        float4 v1 = *(float4*)(p + 4);
        v0.x = (v0.x - mean) * inv * g0[0] + b0[0];
        v0.y = (v0.y - mean) * inv * g0[1] + b0[1];
        v0.z = (v0.z - mean) * inv * g0[2] + b0[2];
        v0.w = (v0.w - mean) * inv * g0[3] + b0[3];
        v1.x = (v1.x - mean) * inv * g0[4] + b0[4];
        v1.y = (v1.y - mean) * inv * g0[5] + b0[5];
        v1.z = (v1.z - mean) * inv * g0[6] + b0[6];
        v1.w = (v1.w - mean) * inv * g0[7] + b0[7];
        *(float4*)p = v0;
        *(float4*)(p + 4) = v1;
    }
}

// ---------------------------------------------------------------------------
// Sine positional embedding + level embed. pos[q][d], shared across batch.
// ---------------------------------------------------------------------------
__global__ __launch_bounds__(256)
void pos_k(float* __restrict__ pos, const float* __restrict__ lemb)
{
    const int q = blockIdx.x;
    const int d = threadIdx.x;
    int lvl, start, S;
    level_of(q, lvl, start, S);
    const int qi = q - start;
    const int r = qi / S, c = qi % S;
    const float twopi = 6.283185307179586f;
    float e; int dd;
    if (d < 128) { e = (float)(r + 1) / ((float)S + 1e-6f) * twopi; dd = d; }
    else         { e = (float)(c + 1) / ((float)S + 1e-6f) * twopi; dd = d - 128; }
    const float dimt = expf(9.210340371976184f * (float)(dd & ~1) / 128.f);
    const float p = e / dimt;
    const float v = (dd & 1) ? cosf(p) : sinf(p);
    pos[(long)q * DD + d] = v + lemb[lvl * DD + d];
}

// q = src + pos  (pos broadcast over batch)
__global__ __launch_bounds__(256)
void add_pos_k(const float* __restrict__ src, const float* __restrict__ pos,
               float* __restrict__ qo)
{
    const long i4 = (long)blockIdx.x * 256 + threadIdx.x;   // exactly B*LQ*D/4
    const long f = i4 * 4;
    const long rem = f % (long)(LQT * DD);
    float4 s = *(const float4*)(src + f);
    const float4 p = *(const float4*)(pos + rem);
    s.x += p.x; s.y += p.y; s.z += p.z; s.w += p.w;
    *(float4*)(qo + f) = s;
}

// softmax over 16 contiguous values per (b,q,h)
__global__ __launch_bounds__(256)
void softmax16_k(float* __restrict__ aw)
{
    const long i = (long)blockIdx.x * 256 + threadIdx.x;  // exactly B*LQ*NH
    float* p = aw + i * 16;
    float v[16];
    #pragma unroll
    for (int j = 0; j < 4; ++j) {
        float4 t4 = *(const float4*)(p + j * 4);
        v[j * 4 + 0] = t4.x; v[j * 4 + 1] = t4.y;
        v[j * 4 + 2] = t4.z; v[j * 4 + 3] = t4.w;
    }
    float mx = v[0];
    #pragma unroll
    for (int j = 1; j < 16; ++j) mx = fmaxf(mx, v[j]);
    float sm = 0.f;
    #pragma unroll
    for (int j = 0; j < 16; ++j) { v[j] = expf(v[j] - mx); sm += v[j]; }
    const float rr = 1.f / sm;
    #pragma unroll
    for (int j = 0; j < 4; ++j) {
        float4 t4 = make_float4(v[j*4+0]*rr, v[j*4+1]*rr, v[j*4+2]*rr, v[j*4+3]*rr);
        *(float4*)(p + j * 4) = t4;
    }
}

// ---------------------------------------------------------------------------
// Multi-scale deformable attention core. Block per (b,q); thread = (h,d).
// ---------------------------------------------------------------------------
__global__ __launch_bounds__(256)
void msdeform_k(const float* __restrict__ val, const float* __restrict__ off,
                const float* __restrict__ aw, float* __restrict__ out)
{
    const int bq = blockIdx.x;
    const int b = bq / LQT, q = bq - b * LQT;
    __shared__ float s_off[256];
    __shared__ float s_aw[128];
    const int t = threadIdx.x;
    s_off[t] = off[(long)bq * 256 + t];
    if (t < 128) s_aw[t] = aw[(long)bq * 128 + t];
    __syncthreads();
    const int h = t >> 5;          // channel c == t == h*32 + d
    int lvl0, start0, S0;
    level_of(q, lvl0, start0, S0);
    const int qi = q - start0;
    const float refx = ((float)(qi % S0) + 0.5f) / (float)S0;
    const float refy = ((float)(qi / S0) + 0.5f) / (float)S0;
    const float* vb = val + (long)b * LQT * DD;
    const int SL[4]  = {96, 48, 24, 12};
    const int STL[4] = {0, 9216, 11520, 12096};
    float acc = 0.f;
    #pragma unroll
    for (int l = 0; l < 4; ++l) {
        const int S = SL[l];
        const float fx = refx * (float)S - 0.5f;
        const float fy = refy * (float)S - 0.5f;
        const float* vlev = vb + (long)STL[l] * DD + t;
        #pragma unroll
        for (int p = 0; p < 4; ++p) {
            const int oidx = ((h * 4 + l) * 4 + p) * 2;
            const float x = fx + s_off[oidx];
            const float y = fy + s_off[oidx + 1];
            const float wat = s_aw[h * 16 + l * 4 + p];
            const float x0 = floorf(x), y0 = floorf(y);
            const float tx = x - x0, ty = y - y0;
            const int ix = (int)x0, iy = (int)y0;
            float samp = 0.f;
            #pragma unroll
            for (int dy = 0; dy < 2; ++dy) {
                const int yi = iy + dy;
                if (yi < 0 || yi >= S) continue;
                const float wy = dy ? ty : 1.f - ty;
                #pragma unroll
                for (int dx = 0; dx < 2; ++dx) {
                    const int xi = ix + dx;
                    if (xi < 0 || xi >= S) continue;
                    const float wx = dx ? tx : 1.f - tx;
                    samp = fmaf(wx * wy, vlev[(long)(yi * S + xi) * DD], samp);
                }
            }
            acc = fmaf(wat, samp, acc);
        }
    }
    out[(long)bq * DD + t] = acc;
}

// LayerNorm over D=256; block per row, thread per channel.
__global__ __launch_bounds__(256)
void layernorm_k(const float* __restrict__ x, const float* __restrict__ g,
                 const float* __restrict__ b, float* __restrict__ out)
{
    const long row = blockIdx.x;
    const int t = threadIdx.x;
    const float v = x[row * DD + t];
    float s = v, sq = v * v;
    #pragma unroll
    for (int o = 32; o > 0; o >>= 1) {
        s += __shfl_down(s, o);
        sq += __shfl_down(sq, o);
    }
    __shared__ float sh[8];
    if ((t & 63) == 0) { sh[t >> 6] = s; sh[4 + (t >> 6)] = sq; }
    __syncthreads();
    const float S = sh[0] + sh[1] + sh[2] + sh[3];
    const float Q = sh[4] + sh[5] + sh[6] + sh[7];
    const float mean = S * (1.f / 256.f);
    const float inv = rsqrtf(Q * (1.f / 256.f) - mean * mean + 1e-5f);
    out[row * DD + t] = (v - mean) * inv * g[t] + b[t];
}

// Tail constants: level_start_index(4), spatial_shapes(8), valid_ratios(16)
__global__ void tail_k(float* __restrict__ o)
{
    const float tv[28] = {0.f, 9216.f, 11520.f, 12096.f,
                          96.f, 96.f, 48.f, 48.f, 24.f, 24.f, 12.f, 12.f,
                          1.f, 1.f, 1.f, 1.f, 1.f, 1.f, 1.f, 1.f,
                          1.f, 1.f, 1.f, 1.f, 1.f, 1.f, 1.f, 1.f};
    const int t = threadIdx.x;
    if (t < 28) o[t] = tv[t];
}

extern "C" void kernel_launch(void* const* d_in, const int* in_sizes, int n_in,
                              void* d_out, int out_size, void* d_ws, size_t ws_size,
                              hipStream_t stream)
{
    const float* xs[4]  = {(const float*)d_in[0], (const float*)d_in[3],
                           (const float*)d_in[6], (const float*)d_in[9]};
    const float* fcw[4] = {(const float*)d_in[1], (const float*)d_in[4],
                           (const float*)d_in[7], (const float*)d_in[10]};
    const float* fcb[4] = {(const float*)d_in[2], (const float*)d_in[5],
                           (const float*)d_in[8], (const float*)d_in[11]};
    const float* gn_g = (const float*)d_in[12];
    const float* gn_b = (const float*)d_in[13];
    const float* lemb = (const float*)d_in[14];
    const float* off_w = (const float*)d_in[15];
    const float* off_b = (const float*)d_in[16];
    const float* aw_w  = (const float*)d_in[17];
    const float* aw_b  = (const float*)d_in[18];
    const float* val_w = (const float*)d_in[19];
    const float* val_b = (const float*)d_in[20];
    const float* out_w = (const float*)d_in[21];
    const float* out_b = (const float*)d_in[22];
    const float* ln1_g = (const float*)d_in[23];
    const float* ln1_b = (const float*)d_in[24];
    const float* l1_w  = (const float*)d_in[25];
    const float* l1_b  = (const float*)d_in[26];
    const float* l2_w  = (const float*)d_in[27];
    const float* l2_b  = (const float*)d_in[28];
    const float* ln2_g = (const float*)d_in[29];
    const float* ln2_b = (const float*)d_in[30];

    float* src = (float*)d_out;                 // (B, LQ, D) lives in d_out
    float* ws = (float*)d_ws;
    float* pos  = ws;                           // 3,133,440
    float* qb   = pos  + 3133440;               // 6,266,880 (also reused as tmp)
    float* offb = qb   + 6266880;               // 6,266,880
    float* awb  = offb + 6266880;               // 3,133,440
    float* valb = awb  + 3133440;               // 6,266,880
    float* msd  = valb + 6266880;               // 6,266,880
    float* fbuf = msd  + 6266880;               // 4,194,304 (FFN hidden chunk)
    (void)in_sizes; (void)n_in; (void)out_size; (void)ws_size;

    const int CINS[4]   = {256, 512, 768, 1024};
    const int SS[4]     = {96, 48, 24, 12};
    const int STARTS[4] = {0, 9216, 11520, 12096};

    // 1) input projections (transA GEMM straight from NCHW x)
    for (int i = 0; i < 4; ++i) {
        const int Ml = SS[i] * SS[i];
        dim3 grid((Ml + 63) / 64, DD / 64, BB);
        gemm_tiled<<<grid, 256, 0, stream>>>(
            xs[i], (long)CINS[i] * Ml, 1,
            fcw[i], fcb[i], nullptr, 0,
            src + (long)STARTS[i] * DD, (long)LQT * DD,
            Ml, DD, CINS[i], 0);
    }
    // 2) group norm (stats over level tokens x 8 channels)
    groupnorm_k<<<dim3(32, 4, BB), 256, 0, stream>>>(src, gn_g, gn_b);
    // 3) positional embedding
    pos_k<<<LQT, 256, 0, stream>>>(pos, lemb);

    // 4) encoder layers
    for (int l = 0; l < 6; ++l) {
        add_pos_k<<<6120, 256, 0, stream>>>(src, pos, qb);
        gemm_tiled<<<dim3(383, 4, 1), 256, 0, stream>>>(
            qb, 0, 0, off_w + (long)l * DD * DD, off_b + l * DD,
            nullptr, 0, offb, 0, MROWS, DD, DD, 0);
        gemm_tiled<<<dim3(383, 2, 1), 256, 0, stream>>>(
            qb, 0, 0, aw_w + (long)l * 128 * DD, aw_b + l * 128,
            nullptr, 0, awb, 0, MROWS, 128, DD, 0);
        gemm_tiled<<<dim3(383, 4, 1), 256, 0, stream>>>(
            src, 0, 0, val_w + (long)l * DD * DD, val_b + l * DD,
            nullptr, 0, valb, 0, MROWS, DD, DD, 0);
        softmax16_k<<<765, 256, 0, stream>>>(awb);
        msdeform_k<<<MROWS, 256, 0, stream>>>(valb, offb, awb, msd);
        // att projection + residual (src)
        gemm_tiled<<<dim3(383, 4, 1), 256, 0, stream>>>(
            msd, 0, 0, out_w + (long)l * DD * DD, out_b + l * DD,
            src, 0, qb, 0, MROWS, DD, DD, 2);
        layernorm_k<<<MROWS, 256, 0, stream>>>(qb, ln1_g + l * DD, ln1_b + l * DD, src);
        // FFN in row chunks (hidden buffer reuse)
        for (int c0 = 0; c0 < MROWS; c0 += 4096) {
            const int rows = (MROWS - c0 < 4096) ? (MROWS - c0) : 4096;
            gemm_tiled<<<dim3((rows + 63) / 64, 16, 1), 256, 0, stream>>>(
                src + (long)c0 * DD, 0, 0, l1_w + (long)l * DFFN * DD, l1_b + l * DFFN,
                nullptr, 0, fbuf, 0, rows, DFFN, DD, 1);
            gemm_tiled<<<dim3((rows + 63) / 64, 4, 1), 256, 0, stream>>>(
                fbuf, 0, 0, l2_w + (long)l * DD * DFFN, l2_b + l * DD,
                src + (long)c0 * DD, 0, qb + (long)c0 * DD, 0, rows, DD, DFFN, 2);
        }
        layernorm_k<<<MROWS, 256, 0, stream>>>(qb, ln2_g + l * DD, ln2_b + l * DD, src);
    }
    // 5) constant tail outputs
    tail_k<<<1, 32, 0, stream>>>(src + (long)BB * LQT * DD);
}

// Round 2
// 3581.568 us; speedup vs baseline: 1.9595x; 1.9595x over previous
//
#include <hip/hip_runtime.h>
#include <math.h>

#define DD 256
#define DFFN 1024
#define LQT 12240
#define BB 2
#define MROWS (BB * LQT)   // 24480

typedef __attribute__((ext_vector_type(8))) short short8v;
typedef __attribute__((ext_vector_type(4))) float floatx4;

__device__ __forceinline__ unsigned short f2bf(float x) {
    unsigned int u = __builtin_bit_cast(unsigned int, x);
    u = (u + 0x7fffu + ((u >> 16) & 1u)) >> 16;
    return (unsigned short)u;
}
__device__ __forceinline__ float bf2f(unsigned short h) {
    unsigned int u = ((unsigned int)h) << 16;
    return __builtin_bit_cast(float, u);
}

__device__ __forceinline__ void level_of(int q, int& lvl, int& start, int& S) {
    if (q < 9216)       { lvl = 0; start = 0;     S = 96; }
    else if (q < 11520) { lvl = 1; start = 9216;  S = 48; }
    else if (q < 12096) { lvl = 2; start = 11520; S = 24; }
    else                { lvl = 3; start = 12096; S = 12; }
}

// ---------------------------------------------------------------------------
// fp32 tiled GEMM (kept only for the 4 input projections, transA path)
// ---------------------------------------------------------------------------
__global__ __launch_bounds__(256)
void gemm_tiled(const float* __restrict__ A, long aZ, int transA,
                const float* __restrict__ W, const float* __restrict__ bias,
                float* __restrict__ C, long cZ,
                int M, int N, int K)
{
    __shared__ float As[16][68];
    __shared__ float Bs[16][68];
    const int z = blockIdx.z;
    A += (long)z * aZ;
    C += (long)z * cZ;
    const int m0 = blockIdx.x * 64;
    const int n0 = blockIdx.y * 64;
    const int t = threadIdx.x;
    const int tx = t & 15, ty = t >> 4;
    float acc[4][4] = {};

    for (int k0 = 0; k0 < K; k0 += 16) {
        if (transA) {
            const int kk = t & 15, mm = (t >> 4) << 2;
            const int gm = m0 + mm;
            float4 v = make_float4(0.f, 0.f, 0.f, 0.f);
            if (gm + 3 < M) {
                v = *(const float4*)(A + (long)(k0 + kk) * M + gm);
            } else if (gm < M) {
                const float* p = A + (long)(k0 + kk) * M;
                v.x = p[gm];
                if (gm + 1 < M) v.y = p[gm + 1];
                if (gm + 2 < M) v.z = p[gm + 2];
            }
            *(float4*)&As[kk][mm] = v;
        } else {
            const int mm = t >> 2, kq = (t & 3) << 2;
            const int gm = m0 + mm;
            float4 v = make_float4(0.f, 0.f, 0.f, 0.f);
            if (gm < M) v = *(const float4*)(A + (long)gm * K + k0 + kq);
            As[kq + 0][mm] = v.x; As[kq + 1][mm] = v.y;
            As[kq + 2][mm] = v.z; As[kq + 3][mm] = v.w;
        }
        {
            const int nn = t >> 2, kq = (t & 3) << 2;
            float4 v = *(const float4*)(W + (long)(n0 + nn) * K + k0 + kq);
            Bs[kq + 0][nn] = v.x; Bs[kq + 1][nn] = v.y;
            Bs[kq + 2][nn] = v.z; Bs[kq + 3][nn] = v.w;
        }
        __syncthreads();
        #pragma unroll
        for (int k = 0; k < 16; ++k) {
            const float4 a4 = *(const float4*)&As[k][ty << 2];
            const float4 b4 = *(const float4*)&Bs[k][tx << 2];
            const float av[4] = {a4.x, a4.y, a4.z, a4.w};
            const float bv[4] = {b4.x, b4.y, b4.z, b4.w};
            #pragma unroll
            for (int i = 0; i < 4; ++i)
                #pragma unroll
                for (int j = 0; j < 4; ++j)
                    acc[i][j] = fmaf(av[i], bv[j], acc[i][j]);
        }
        __syncthreads();
    }

    #pragma unroll
    for (int i = 0; i < 4; ++i) {
        const int gm = m0 + (ty << 2) + i;
        if (gm >= M) continue;
        #pragma unroll
        for (int j = 0; j < 4; ++j) {
            const int gn = n0 + (tx << 2) + j;
            C[(long)gm * N + gn] = acc[i][j] + bias[gn];
        }
    }
}

// ---------------------------------------------------------------------------
// bf16 MFMA GEMM: C[M,N] = op(A[M,K] @ W[N,K]^T + bias)
// 128x128 tile, 4 waves (2x2), each wave 64x64 (4x4 frags of 16x16x32).
// LDS layout [kblk][row][8] so a fragment is one ds_read_b128.
// op: 0 = f32 out; 1 = relu -> bf16 out; 2 = +R f32 out; 3 = bf16 out
// ---------------------------------------------------------------------------
__global__ __launch_bounds__(256)
void gemm_bf16(const unsigned short* __restrict__ A,
               const unsigned short* __restrict__ W,
               const float* __restrict__ bias, const float* __restrict__ R,
               float* __restrict__ Cf, unsigned short* __restrict__ Ch,
               int M, int N, int K, int op)
{
    __shared__ alignas(16) unsigned short As[4][128][8];
    __shared__ alignas(16) unsigned short Bs[4][128][8];
    const int t = threadIdx.x;
    const int m0 = blockIdx.x * 128, n0 = blockIdx.y * 128;
    const int w = t >> 6, l = t & 63;
    const int wm = w >> 1, wn = w & 1;
    // staging: thread t loads 32B of row sr, k-half hf (16 elems)
    const int sr = t >> 1, hf = t & 1;
    int gr = m0 + sr; if (gr >= M) gr = M - 1;
    const unsigned short* pa = A + (long)gr * K + hf * 16;
    const unsigned short* pb = W + (long)(n0 + sr) * K + hf * 16;
    const int kb = l >> 4, lr = l & 15;

    floatx4 acc[4][4];
    #pragma unroll
    for (int m = 0; m < 4; ++m)
        #pragma unroll
        for (int n = 0; n < 4; ++n)
            acc[m][n] = (floatx4){0.f, 0.f, 0.f, 0.f};

    for (int k0 = 0; k0 < K; k0 += 32) {
        const uint4 a0 = *(const uint4*)(pa);
        const uint4 a1 = *(const uint4*)(pa + 8);
        const uint4 b0 = *(const uint4*)(pb);
        const uint4 b1 = *(const uint4*)(pb + 8);
        pa += 32; pb += 32;
        __syncthreads();   // previous iteration's LDS reads done
        *(uint4*)&As[hf * 2][sr][0]     = a0;
        *(uint4*)&As[hf * 2 + 1][sr][0] = a1;
        *(uint4*)&Bs[hf * 2][sr][0]     = b0;
        *(uint4*)&Bs[hf * 2 + 1][sr][0] = b1;
        __syncthreads();
        short8v av[4], bv[4];
        #pragma unroll
        for (int m = 0; m < 4; ++m)
            av[m] = *(const short8v*)&As[kb][wm * 64 + m * 16 + lr][0];
        #pragma unroll
        for (int n = 0; n < 4; ++n)
            bv[n] = *(const short8v*)&Bs[kb][wn * 64 + n * 16 + lr][0];
        #pragma unroll
        for (int m = 0; m < 4; ++m)
            #pragma unroll
            for (int n = 0; n < 4; ++n)
                acc[m][n] = __builtin_amdgcn_mfma_f32_16x16x32_bf16(
                    av[m], bv[n], acc[m][n], 0, 0, 0);
    }

    const int lh = l >> 4;
    #pragma unroll
    for (int m = 0; m < 4; ++m) {
        const int row0 = m0 + wm * 64 + m * 16 + lh * 4;
        #pragma unroll
        for (int n = 0; n < 4; ++n) {
            const int col = n0 + wn * 64 + n * 16 + lr;
            const float bi = bias[col];
            #pragma unroll
            for (int r = 0; r < 4; ++r) {
                const int row = row0 + r;
                if (row >= M) continue;
                const long o = (long)row * N + col;
                float v = acc[m][n][r] + bi;
                if (op == 0)      Cf[o] = v;
                else if (op == 1) Ch[o] = f2bf(fmaxf(v, 0.f));
                else if (op == 2) Cf[o] = v + R[o];
                else              Ch[o] = f2bf(v);
            }
        }
    }
}

// ---------------------------------------------------------------------------
// GroupNorm (stats over level tokens x 8 channels); writes f32 + bf16 copies
// ---------------------------------------------------------------------------
__global__ __launch_bounds__(256)
void groupnorm_k(float* __restrict__ src, unsigned short* __restrict__ srch,
                 const float* __restrict__ gg, const float* __restrict__ gb)
{
    const int grp = blockIdx.x;
    const int lvl = blockIdx.y;
    const int b   = blockIdx.z;
    const int sizes[4]  = {9216, 2304, 576, 144};
    const int starts[4] = {0, 9216, 11520, 12096};
    const int Ml = sizes[lvl];
    const long boff = ((long)b * LQT + starts[lvl]) * DD + grp * 8;
    float* base = src + boff;
    unsigned short* baseh = srch + boff;
    const int t = threadIdx.x;
    float sum = 0.f, ssq = 0.f;
    for (int r = t; r < Ml; r += 256) {
        const float* p = base + (long)r * DD;
        float4 v0 = *(const float4*)p;
        float4 v1 = *(const float4*)(p + 4);
        sum += (v0.x + v0.y) + (v0.z + v0.w) + (v1.x + v1.y) + (v1.z + v1.w);
        ssq += v0.x * v0.x + v0.y * v0.y + v0.z * v0.z + v0.w * v0.w
             + v1.x * v1.x + v1.y * v1.y + v1.z * v1.z + v1.w * v1.w;
    }
    #pragma unroll
    for (int o = 32; o > 0; o >>= 1) {
        sum += __shfl_down(sum, o);
        ssq += __shfl_down(ssq, o);
    }
    __shared__ float sh[8];
    if ((t & 63) == 0) { sh[t >> 6] = sum; sh[4 + (t >> 6)] = ssq; }
    __syncthreads();
    const float tot = sh[0] + sh[1] + sh[2] + sh[3];
    const float tq  = sh[4] + sh[5] + sh[6] + sh[7];
    const float cnt = (float)(Ml * 8);
    const float mean = tot / cnt;
    const float inv = rsqrtf(tq / cnt - mean * mean + 1e-5f);
    float g0[8], b0[8];
    #pragma unroll
    for (int c = 0; c < 8; ++c) {
        g0[c] = gg[lvl * DD + grp * 8 + c];
        b0[c] = gb[lvl * DD + grp * 8 + c];
    }
    for (int r = t; r < Ml; r += 256) {
        float* p = base + (long)r * DD;
        unsigned short* ph = baseh + (long)r * DD;
        float4 v0 = *(float4*)p;
        float4 v1 = *(float4*)(p + 4);
        float o_[8];
        o_[0] = (v0.x - mean) * inv * g0[0] + b0[0];
        o_[1] = (v0.y - mean) * inv * g0[1] + b0[1];
        o_[2] = (v0.z - mean) * inv * g0[2] + b0[2];
        o_[3] = (v0.w - mean) * inv * g0[3] + b0[3];
        o_[4] = (v1.x - mean) * inv * g0[4] + b0[4];
        o_[5] = (v1.y - mean) * inv * g0[5] + b0[5];
        o_[6] = (v1.z - mean) * inv * g0[6] + b0[6];
        o_[7] = (v1.w - mean) * inv * g0[7] + b0[7];
        *(float4*)p       = make_float4(o_[0], o_[1], o_[2], o_[3]);
        *(float4*)(p + 4) = make_float4(o_[4], o_[5], o_[6], o_[7]);
        ushort4 h0, h1;
        h0.x = f2bf(o_[0]); h0.y = f2bf(o_[1]); h0.z = f2bf(o_[2]); h0.w = f2bf(o_[3]);
        h1.x = f2bf(o_[4]); h1.y = f2bf(o_[5]); h1.z = f2bf(o_[6]); h1.w = f2bf(o_[7]);
        *(ushort4*)ph       = h0;
        *(ushort4*)(ph + 4) = h1;
    }
}

__global__ __launch_bounds__(256)
void pos_k(float* __restrict__ pos, const float* __restrict__ lemb)
{
    const int q = blockIdx.x;
    const int d = threadIdx.x;
    int lvl, start, S;
    level_of(q, lvl, start, S);
    const int qi = q - start;
    const int r = qi / S, c = qi % S;
    const float twopi = 6.283185307179586f;
    float e; int dd;
    if (d < 128) { e = (float)(r + 1) / ((float)S + 1e-6f) * twopi; dd = d; }
    else         { e = (float)(c + 1) / ((float)S + 1e-6f) * twopi; dd = d - 128; }
    const float dimt = expf(9.210340371976184f * (float)(dd & ~1) / 128.f);
    const float p = e / dimt;
    const float v = (dd & 1) ? cosf(p) : sinf(p);
    pos[(long)q * DD + d] = v + lemb[lvl * DD + d];
}

// q_bf = bf16(src + pos)
__global__ __launch_bounds__(256)
void add_pos_bf_k(const float* __restrict__ src, const float* __restrict__ pos,
                  unsigned short* __restrict__ q)
{
    const long i = ((long)blockIdx.x * 256 + threadIdx.x) * 4;
    const long rem = i % (long)(LQT * DD);
    const float4 s = *(const float4*)(src + i);
    const float4 p = *(const float4*)(pos + rem);
    ushort4 o;
    o.x = f2bf(s.x + p.x); o.y = f2bf(s.y + p.y);
    o.z = f2bf(s.z + p.z); o.w = f2bf(s.w + p.w);
    *(ushort4*)(q + i) = o;
}

__global__ __launch_bounds__(256)
void softmax16_k(float* __restrict__ aw)
{
    const long i = (long)blockIdx.x * 256 + threadIdx.x;
    float* p = aw + i * 16;
    float v[16];
    #pragma unroll
    for (int j = 0; j < 4; ++j) {
        float4 t4 = *(const float4*)(p + j * 4);
        v[j * 4 + 0] = t4.x; v[j * 4 + 1] = t4.y;
        v[j * 4 + 2] = t4.z; v[j * 4 + 3] = t4.w;
    }
    float mx = v[0];
    #pragma unroll
    for (int j = 1; j < 16; ++j) mx = fmaxf(mx, v[j]);
    float sm = 0.f;
    #pragma unroll
    for (int j = 0; j < 16; ++j) { v[j] = expf(v[j] - mx); sm += v[j]; }
    const float rr = 1.f / sm;
    #pragma unroll
    for (int j = 0; j < 4; ++j) {
        float4 t4 = make_float4(v[j*4+0]*rr, v[j*4+1]*rr, v[j*4+2]*rr, v[j*4+3]*rr);
        *(float4*)(p + j * 4) = t4;
    }
}

// ---------------------------------------------------------------------------
// Deformable attention v2: phase A (128 threads) precomputes per-(h,l,p)
// corner bases + weights into LDS; phase B gathers bf16 values.
// ---------------------------------------------------------------------------
__global__ __launch_bounds__(256)
void msdeform_k(const unsigned short* __restrict__ val,
                const unsigned short* __restrict__ off,
                const float* __restrict__ aw,
                unsigned short* __restrict__ out)
{
    const int bq = blockIdx.x;
    const int b = bq / LQT, q = bq - b * LQT;
    __shared__ int   s_base[128][4];
    __shared__ float s_w[128][4];
    const int t = threadIdx.x;
    int lvl0, start0, S0;
    level_of(q, lvl0, start0, S0);
    const int qi = q - start0;
    if (t < 128) {
        const int l = (t >> 2) & 3;
        const int SL[4]  = {96, 48, 24, 12};
        const int STL[4] = {0, 9216, 11520, 12096};
        const int S = SL[l];
        const float refx = ((float)(qi % S0) + 0.5f) / (float)S0;
        const float refy = ((float)(qi / S0) + 0.5f) / (float)S0;
        const float x = refx * (float)S - 0.5f + bf2f(off[(long)bq * 256 + 2 * t]);
        const float y = refy * (float)S - 0.5f + bf2f(off[(long)bq * 256 + 2 * t + 1]);
        const float wat = aw[(long)bq * 128 + t];
        const float x0 = floorf(x), y0 = floorf(y);
        const float tx = x - x0, ty = y - y0;
        const int ix = (int)x0, iy = (int)y0;
        #pragma unroll
        for (int c = 0; c < 4; ++c) {
            const int dx = c & 1, dy = c >> 1;
            const int xi = ix + dx, yi = iy + dy;
            const bool ok = (xi >= 0) && (xi < S) && (yi >= 0) && (yi < S);
            const int cx = min(max(xi, 0), S - 1);
            const int cy = min(max(yi, 0), S - 1);
            const float wxy = (dx ? tx : 1.f - tx) * (dy ? ty : 1.f - ty);
            s_base[t][c] = (STL[l] + cy * S + cx) << 8;
            s_w[t][c] = ok ? wxy * wat : 0.f;
        }
    }
    __syncthreads();
    const int h = t >> 5;
    const unsigned short* vb = val + (long)b * (LQT * DD) + t;
    float acc = 0.f;
    #pragma unroll
    for (int lp = 0; lp < 16; ++lp) {
        const int task = h * 16 + lp;
        #pragma unroll
        for (int c = 0; c < 4; ++c)
            acc = fmaf(s_w[task][c], bf2f(vb[s_base[task][c]]), acc);
    }
    out[(long)bq * DD + t] = f2bf(acc);
}

// LayerNorm over D=256; writes f32 + bf16
__global__ __launch_bounds__(256)
void layernorm_k(const float* __restrict__ x, const float* __restrict__ g,
                 const float* __restrict__ b, float* __restrict__ outf,
                 unsigned short* __restrict__ outh)
{
    const long row = blockIdx.x;
    const int t = threadIdx.x;
    const float v = x[row * DD + t];
    float s = v, sq = v * v;
    #pragma unroll
    for (int o = 32; o > 0; o >>= 1) {
        s += __shfl_down(s, o);
        sq += __shfl_down(sq, o);
    }
    __shared__ float sh[8];
    if ((t & 63) == 0) { sh[t >> 6] = s; sh[4 + (t >> 6)] = sq; }
    __syncthreads();
    const float S = sh[0] + sh[1] + sh[2] + sh[3];
    const float Q = sh[4] + sh[5] + sh[6] + sh[7];
    const float mean = S * (1.f / 256.f);
    const float inv = rsqrtf(Q * (1.f / 256.f) - mean * mean + 1e-5f);
    const float y = (v - mean) * inv * g[t] + b[t];
    outf[row * DD + t] = y;
    outh[row * DD + t] = f2bf(y);
}

// f32 -> bf16 convert (n multiple of 4)
__global__ __launch_bounds__(256)
void cvt_k(const float* __restrict__ in, unsigned short* __restrict__ out, long n)
{
    const long i = ((long)blockIdx.x * 256 + threadIdx.x) * 4;
    if (i >= n) return;
    const float4 v = *(const float4*)(in + i);
    ushort4 o;
    o.x = f2bf(v.x); o.y = f2bf(v.y); o.z = f2bf(v.z); o.w = f2bf(v.w);
    *(ushort4*)(out + i) = o;
}

__global__ void tail_k(float* __restrict__ o)
{
    const float tv[28] = {0.f, 9216.f, 11520.f, 12096.f,
                          96.f, 96.f, 48.f, 48.f, 24.f, 24.f, 12.f, 12.f,
                          1.f, 1.f, 1.f, 1.f, 1.f, 1.f, 1.f, 1.f,
                          1.f, 1.f, 1.f, 1.f, 1.f, 1.f, 1.f, 1.f};
    const int t = threadIdx.x;
    if (t < 28) o[t] = tv[t];
}

extern "C" void kernel_launch(void* const* d_in, const int* in_sizes, int n_in,
                              void* d_out, int out_size, void* d_ws, size_t ws_size,
                              hipStream_t stream)
{
    const float* xs[4]  = {(const float*)d_in[0], (const float*)d_in[3],
                           (const float*)d_in[6], (const float*)d_in[9]};
    const float* fcw[4] = {(const float*)d_in[1], (const float*)d_in[4],
                           (const float*)d_in[7], (const float*)d_in[10]};
    const float* fcb[4] = {(const float*)d_in[2], (const float*)d_in[5],
                           (const float*)d_in[8], (const float*)d_in[11]};
    const float* gn_g = (const float*)d_in[12];
    const float* gn_b = (const float*)d_in[13];
    const float* lemb = (const float*)d_in[14];
    const float* off_w = (const float*)d_in[15];
    const float* off_b = (const float*)d_in[16];
    const float* aw_w  = (const float*)d_in[17];
    const float* aw_b  = (const float*)d_in[18];
    const float* val_w = (const float*)d_in[19];
    const float* val_b = (const float*)d_in[20];
    const float* out_w = (const float*)d_in[21];
    const float* out_b = (const float*)d_in[22];
    const float* ln1_g = (const float*)d_in[23];
    const float* ln1_b = (const float*)d_in[24];
    const float* l1_w  = (const float*)d_in[25];
    const float* l1_b  = (const float*)d_in[26];
    const float* l2_w  = (const float*)d_in[27];
    const float* l2_b  = (const float*)d_in[28];
    const float* ln2_g = (const float*)d_in[29];
    const float* ln2_b = (const float*)d_in[30];

    float* src = (float*)d_out;                 // (B, LQ, D)
    float* ws = (float*)d_ws;
    float* pos = ws;                            // 3,133,440 f32
    float* awb = pos + 3133440;                 // 3,133,440 f32
    float* tmp = awb + 3133440;                 // 6,266,880 f32
    unsigned short* q_bf   = (unsigned short*)(tmp + 6266880);
    unsigned short* src_bf = q_bf   + 6266880;
    unsigned short* msd_bf = src_bf + 6266880;
    unsigned short* val_bf = msd_bf + 6266880;
    unsigned short* off_bf = val_bf + 6266880;
    unsigned short* hid_bf = off_bf + 6266880;  // 8,388,608 (8192x1024)
    unsigned short* wb     = hid_bf + 8388608;
    unsigned short* wb_off = wb;                // 6*65536
    unsigned short* wb_aw  = wb_off + 393216;   // 6*32768
    unsigned short* wb_val = wb_aw  + 196608;   // 6*65536
    unsigned short* wb_out = wb_val + 393216;   // 6*65536
    unsigned short* wb_l1  = wb_out + 393216;   // 6*262144
    unsigned short* wb_l2  = wb_l1  + 1572864;  // 6*262144
    (void)in_sizes; (void)n_in; (void)out_size; (void)ws_size;

    const int CINS[4]   = {256, 512, 768, 1024};
    const int SS[4]     = {96, 48, 24, 12};
    const int STARTS[4] = {0, 9216, 11520, 12096};

    // 0) weights -> bf16
    cvt_k<<<384,  256, 0, stream>>>(off_w, wb_off, 393216);
    cvt_k<<<192,  256, 0, stream>>>(aw_w,  wb_aw,  196608);
    cvt_k<<<384,  256, 0, stream>>>(val_w, wb_val, 393216);
    cvt_k<<<384,  256, 0, stream>>>(out_w, wb_out, 393216);
    cvt_k<<<1536, 256, 0, stream>>>(l1_w,  wb_l1,  1572864);
    cvt_k<<<1536, 256, 0, stream>>>(l2_w,  wb_l2,  1572864);

    // 1) input projections (fp32, transA from NCHW)
    for (int i = 0; i < 4; ++i) {
        const int Ml = SS[i] * SS[i];
        dim3 grid((Ml + 63) / 64, DD / 64, BB);
        gemm_tiled<<<grid, 256, 0, stream>>>(
            xs[i], (long)CINS[i] * Ml, 1,
            fcw[i], fcb[i],
            src + (long)STARTS[i] * DD, (long)LQT * DD,
            Ml, DD, CINS[i]);
    }
    // 2) group norm -> src (f32) + src_bf
    groupnorm_k<<<dim3(32, 4, BB), 256, 0, stream>>>(src, src_bf, gn_g, gn_b);
    // 3) positional embedding
    pos_k<<<LQT, 256, 0, stream>>>(pos, lemb);

    // 4) encoder layers
    for (int l = 0; l < 6; ++l) {
        add_pos_bf_k<<<6120, 256, 0, stream>>>(src, pos, q_bf);
        gemm_bf16<<<dim3(192, 2), 256, 0, stream>>>(
            q_bf, wb_off + (long)l * 65536, off_b + l * DD, nullptr,
            nullptr, off_bf, MROWS, DD, DD, 3);
        gemm_bf16<<<dim3(192, 1), 256, 0, stream>>>(
            q_bf, wb_aw + (long)l * 32768, aw_b + l * 128, nullptr,
            awb, nullptr, MROWS, 128, DD, 0);
        gemm_bf16<<<dim3(192, 2), 256, 0, stream>>>(
            src_bf, wb_val + (long)l * 65536, val_b + l * DD, nullptr,
            nullptr, val_bf, MROWS, DD, DD, 3);
        softmax16_k<<<765, 256, 0, stream>>>(awb);
        msdeform_k<<<MROWS, 256, 0, stream>>>(val_bf, off_bf, awb, msd_bf);
        gemm_bf16<<<dim3(192, 2), 256, 0, stream>>>(
            msd_bf, wb_out + (long)l * 65536, out_b + l * DD, src,
            tmp, nullptr, MROWS, DD, DD, 2);
        layernorm_k<<<MROWS, 256, 0, stream>>>(tmp, ln1_g + l * DD, ln1_b + l * DD,
                                               src, src_bf);
        for (int c0 = 0; c0 < MROWS; c0 += 8192) {
            const int rows = (MROWS - c0 < 8192) ? (MROWS - c0) : 8192;
            const int gx = (rows + 127) / 128;
            gemm_bf16<<<dim3(gx, 8), 256, 0, stream>>>(
                src_bf + (long)c0 * DD, wb_l1 + (long)l * 262144,
                l1_b + l * DFFN, nullptr,
                nullptr, hid_bf, rows, DFFN, DD, 1);
            gemm_bf16<<<dim3(gx, 2), 256, 0, stream>>>(
                hid_bf, wb_l2 + (long)l * 262144,
                l2_b + l * DD, src + (long)c0 * DD,
                tmp + (long)c0 * DD, nullptr, rows, DD, DFFN, 2);
        }
        layernorm_k<<<MROWS, 256, 0, stream>>>(tmp, ln2_g + l * DD, ln2_b + l * DD,
                                               src, src_bf);
    }
    // 5) constant tail outputs
    tail_k<<<1, 32, 0, stream>>>(src + (long)BB * LQT * DD);
}

// Round 3
// 2054.700 us; speedup vs baseline: 3.4157x; 1.7431x over previous
//
#include <hip/hip_runtime.h>
#include <math.h>

#define DD 256
#define DFFN 1024
#define LQT 12240
#define BB 2
#define MROWS (BB * LQT)   // 24480

typedef __attribute__((ext_vector_type(8))) short short8v;
typedef __attribute__((ext_vector_type(4))) float floatx4;
typedef unsigned short ushort_t;

__device__ __forceinline__ unsigned short f2bf(float x) {
    unsigned int u = __builtin_bit_cast(unsigned int, x);
    u = (u + 0x7fffu + ((u >> 16) & 1u)) >> 16;
    return (unsigned short)u;
}
__device__ __forceinline__ float bf2f(unsigned short h) {
    unsigned int u = ((unsigned int)h) << 16;
    return __builtin_bit_cast(float, u);
}

__device__ __forceinline__ void gload16(const unsigned short* g, unsigned short* lds) {
    __builtin_amdgcn_global_load_lds(
        (const __attribute__((address_space(1))) unsigned int*)g,
        (__attribute__((address_space(3))) unsigned int*)lds, 16, 0, 0);
}

__device__ __forceinline__ void level_of(int q, int& lvl, int& start, int& S) {
    if (q < 9216)       { lvl = 0; start = 0;     S = 96; }
    else if (q < 11520) { lvl = 1; start = 9216;  S = 48; }
    else if (q < 12096) { lvl = 2; start = 11520; S = 24; }
    else                { lvl = 3; start = 12096; S = 12; }
}

// ---------------------------------------------------------------------------
// BM=64 x BN=128 bf16 MFMA GEMM with global_load_lds staging.
// op: 0 = f32 out (+z batching); 2 = +R f32 out; 3 = bf16 out;
//     4 = merged off/aw: blocks with n0<256 -> Ch (stride 256), n0>=256 -> Cf (stride 128, W2/bias2)
// ---------------------------------------------------------------------------
__global__ __launch_bounds__(256)
void gemm64(const unsigned short* __restrict__ A, long aZ,
            const unsigned short* __restrict__ W,
            const unsigned short* __restrict__ W2,
            const float* __restrict__ bias, const float* __restrict__ bias2,
            const float* __restrict__ R,
            float* __restrict__ Cf, long cZ, unsigned short* __restrict__ Ch,
            int M, int N, int K, int op)
{
    __shared__ alignas(16) unsigned short As[4][64][8];
    __shared__ alignas(16) unsigned short Bs[4][128][8];
    const int t = threadIdx.x;
    const int z = blockIdx.z;
    A  += (long)z * aZ;
    if (Cf) Cf += (long)z * cZ;
    const int m0 = blockIdx.x * 64;
    const int n0 = blockIdx.y * 128;
    const int wv = __builtin_amdgcn_readfirstlane(t >> 6);
    const int lane = t & 63;
    const int wm = wv >> 1, wn = wv & 1;
    const int kb = lane >> 4, lr = lane & 15;

    const unsigned short* Wb = W;
    const float* bi = bias;
    int nb = n0;
    if (op == 4 && n0 >= 256) { Wb = W2; bi = bias2; nb = n0 - 256; }

    const int ar = min(m0 + lane, M - 1);
    const unsigned short* gA  = A  + (long)ar * K + wv * 8;
    const unsigned short* gB0 = Wb + (long)(nb + lane) * K + wv * 8;
    const unsigned short* gB1 = Wb + (long)(nb + 64 + lane) * K + wv * 8;

    floatx4 acc[2][4];
    #pragma unroll
    for (int m = 0; m < 2; ++m)
        #pragma unroll
        for (int n = 0; n < 4; ++n)
            acc[m][n] = (floatx4){0.f, 0.f, 0.f, 0.f};

    for (int k0 = 0; k0 < K; k0 += 32) {
        __syncthreads();                     // prev LDS reads done
        gload16(gA,  &As[wv][0][0]);
        gload16(gB0, &Bs[wv][0][0]);
        gload16(gB1, &Bs[wv][64][0]);
        gA += 32; gB0 += 32; gB1 += 32;
        __syncthreads();                     // loads landed
        short8v av[2], bv[4];
        #pragma unroll
        for (int m = 0; m < 2; ++m)
            av[m] = *(const short8v*)&As[kb][wm * 32 + m * 16 + lr][0];
        #pragma unroll
        for (int n = 0; n < 4; ++n)
            bv[n] = *(const short8v*)&Bs[kb][wn * 64 + n * 16 + lr][0];
        #pragma unroll
        for (int m = 0; m < 2; ++m)
            #pragma unroll
            for (int n = 0; n < 4; ++n)
                acc[m][n] = __builtin_amdgcn_mfma_f32_16x16x32_bf16(
                    av[m], bv[n], acc[m][n], 0, 0, 0);
    }

    const int lh = lane >> 4;
    #pragma unroll
    for (int m = 0; m < 2; ++m) {
        const int row0 = m0 + wm * 32 + m * 16 + lh * 4;
        #pragma unroll
        for (int n = 0; n < 4; ++n) {
            const int col = n0 + wn * 64 + n * 16 + lr;
            #pragma unroll
            for (int r = 0; r < 4; ++r) {
                const int row = row0 + r;
                if (row >= M) continue;
                float v = acc[m][n][r];
                if (op == 4) {
                    if (n0 < 256) Ch[(long)row * 256 + col] = f2bf(v + bi[col]);
                    else          Cf[(long)row * 128 + (col - 256)] = v + bi[col - 256];
                } else {
                    v += bias[col];
                    const long o = (long)row * N + col;
                    if (op == 0)      Cf[o] = v;
                    else if (op == 2) Cf[o] = v + R[o];
                    else              Ch[o] = f2bf(v);
                }
            }
        }
    }
}

// ---------------------------------------------------------------------------
// BM=128 x BN=128 variant for FFN1 (relu -> bf16 out)
// ---------------------------------------------------------------------------
__global__ __launch_bounds__(256)
void gemm128(const unsigned short* __restrict__ A,
             const unsigned short* __restrict__ W,
             const float* __restrict__ bias, unsigned short* __restrict__ Ch,
             int M, int N, int K)
{
    __shared__ alignas(16) unsigned short As[4][128][8];
    __shared__ alignas(16) unsigned short Bs[4][128][8];
    const int t = threadIdx.x;
    const int m0 = blockIdx.x * 128;
    const int n0 = blockIdx.y * 128;
    const int wv = __builtin_amdgcn_readfirstlane(t >> 6);
    const int lane = t & 63;
    const int wm = wv >> 1, wn = wv & 1;
    const int kb = lane >> 4, lr = lane & 15;

    const int r0 = min(m0 + lane, M - 1);
    const int r1 = min(m0 + 64 + lane, M - 1);
    const unsigned short* gA0 = A + (long)r0 * K + wv * 8;
    const unsigned short* gA1 = A + (long)r1 * K + wv * 8;
    const unsigned short* gB0 = W + (long)(n0 + lane) * K + wv * 8;
    const unsigned short* gB1 = W + (long)(n0 + 64 + lane) * K + wv * 8;

    floatx4 acc[4][4];
    #pragma unroll
    for (int m = 0; m < 4; ++m)
        #pragma unroll
        for (int n = 0; n < 4; ++n)
            acc[m][n] = (floatx4){0.f, 0.f, 0.f, 0.f};

    for (int k0 = 0; k0 < K; k0 += 32) {
        __syncthreads();
        gload16(gA0, &As[wv][0][0]);
        gload16(gA1, &As[wv][64][0]);
        gload16(gB0, &Bs[wv][0][0]);
        gload16(gB1, &Bs[wv][64][0]);
        gA0 += 32; gA1 += 32; gB0 += 32; gB1 += 32;
        __syncthreads();
        short8v av[4], bv[4];
        #pragma unroll
        for (int m = 0; m < 4; ++m)
            av[m] = *(const short8v*)&As[kb][wm * 64 + m * 16 + lr][0];
        #pragma unroll
        for (int n = 0; n < 4; ++n)
            bv[n] = *(const short8v*)&Bs[kb][wn * 64 + n * 16 + lr][0];
        #pragma unroll
        for (int m = 0; m < 4; ++m)
            #pragma unroll
            for (int n = 0; n < 4; ++n)
                acc[m][n] = __builtin_amdgcn_mfma_f32_16x16x32_bf16(
                    av[m], bv[n], acc[m][n], 0, 0, 0);
    }

    const int lh = lane >> 4;
    #pragma unroll
    for (int m = 0; m < 4; ++m) {
        const int row0 = m0 + wm * 64 + m * 16 + lh * 4;
        #pragma unroll
        for (int n = 0; n < 4; ++n) {
            const int col = n0 + wn * 64 + n * 16 + lr;
            const float b = bias[col];
            #pragma unroll
            for (int r = 0; r < 4; ++r) {
                const int row = row0 + r;
                if (row >= M) continue;
                Ch[(long)row * N + col] = f2bf(fmaxf(acc[m][n][r] + b, 0.f));
            }
        }
    }
}

// ---------------------------------------------------------------------------
// transpose (C, Ml) f32 -> (Ml, C) bf16, batch via blockIdx.z
// ---------------------------------------------------------------------------
__global__ __launch_bounds__(256)
void tp_k(const float* __restrict__ x, unsigned short* __restrict__ xt,
          int C, int Ml)
{
    __shared__ float tile[32][33];
    const int m0 = blockIdx.x * 32, c0 = blockIdx.y * 32;
    const int zb = blockIdx.z;
    const float* px = x + (long)zb * C * Ml;
    unsigned short* pxt = xt + (long)zb * Ml * C;
    const int t = threadIdx.x;
    {
        const int cl = t >> 3, m4 = (t & 7) * 4;
        const int gm = m0 + m4;
        if (gm < Ml) {
            const float4 v = *(const float4*)(px + (long)(c0 + cl) * Ml + gm);
            tile[cl][m4 + 0] = v.x; tile[cl][m4 + 1] = v.y;
            tile[cl][m4 + 2] = v.z; tile[cl][m4 + 3] = v.w;
        }
    }
    __syncthreads();
    {
        const int ml = t >> 3, c4 = (t & 7) * 4;
        const int gm = m0 + ml;
        if (gm < Ml) {
            ushort4 o;
            o.x = f2bf(tile[c4 + 0][ml]);
            o.y = f2bf(tile[c4 + 1][ml]);
            o.z = f2bf(tile[c4 + 2][ml]);
            o.w = f2bf(tile[c4 + 3][ml]);
            *(ushort4*)(pxt + (long)gm * C + c0 + c4) = o;
        }
    }
}

// ---------------------------------------------------------------------------
// GroupNorm; writes f32 + bf16
// ---------------------------------------------------------------------------
__global__ __launch_bounds__(256)
void groupnorm_k(float* __restrict__ src, unsigned short* __restrict__ srch,
                 const float* __restrict__ gg, const float* __restrict__ gb)
{
    const int grp = blockIdx.x;
    const int lvl = blockIdx.y;
    const int b   = blockIdx.z;
    const int sizes[4]  = {9216, 2304, 576, 144};
    const int starts[4] = {0, 9216, 11520, 12096};
    const int Ml = sizes[lvl];
    const long boff = ((long)b * LQT + starts[lvl]) * DD + grp * 8;
    float* base = src + boff;
    unsigned short* baseh = srch + boff;
    const int t = threadIdx.x;
    float sum = 0.f, ssq = 0.f;
    for (int r = t; r < Ml; r += 256) {
        const float* p = base + (long)r * DD;
        float4 v0 = *(const float4*)p;
        float4 v1 = *(const float4*)(p + 4);
        sum += (v0.x + v0.y) + (v0.z + v0.w) + (v1.x + v1.y) + (v1.z + v1.w);
        ssq += v0.x * v0.x + v0.y * v0.y + v0.z * v0.z + v0.w * v0.w
             + v1.x * v1.x + v1.y * v1.y + v1.z * v1.z + v1.w * v1.w;
    }
    #pragma unroll
    for (int o = 32; o > 0; o >>= 1) {
        sum += __shfl_down(sum, o);
        ssq += __shfl_down(ssq, o);
    }
    __shared__ float sh[8];
    if ((t & 63) == 0) { sh[t >> 6] = sum; sh[4 + (t >> 6)] = ssq; }
    __syncthreads();
    const float tot = sh[0] + sh[1] + sh[2] + sh[3];
    const float tq  = sh[4] + sh[5] + sh[6] + sh[7];
    const float cnt = (float)(Ml * 8);
    const float mean = tot / cnt;
    const float inv = rsqrtf(tq / cnt - mean * mean + 1e-5f);
    float g0[8], b0[8];
    #pragma unroll
    for (int c = 0; c < 8; ++c) {
        g0[c] = gg[lvl * DD + grp * 8 + c];
        b0[c] = gb[lvl * DD + grp * 8 + c];
    }
    for (int r = t; r < Ml; r += 256) {
        float* p = base + (long)r * DD;
        unsigned short* ph = baseh + (long)r * DD;
        float4 v0 = *(float4*)p;
        float4 v1 = *(float4*)(p + 4);
        float o_[8];
        o_[0] = (v0.x - mean) * inv * g0[0] + b0[0];
        o_[1] = (v0.y - mean) * inv * g0[1] + b0[1];
        o_[2] = (v0.z - mean) * inv * g0[2] + b0[2];
        o_[3] = (v0.w - mean) * inv * g0[3] + b0[3];
        o_[4] = (v1.x - mean) * inv * g0[4] + b0[4];
        o_[5] = (v1.y - mean) * inv * g0[5] + b0[5];
        o_[6] = (v1.z - mean) * inv * g0[6] + b0[6];
        o_[7] = (v1.w - mean) * inv * g0[7] + b0[7];
        *(float4*)p       = make_float4(o_[0], o_[1], o_[2], o_[3]);
        *(float4*)(p + 4) = make_float4(o_[4], o_[5], o_[6], o_[7]);
        ushort4 h0, h1;
        h0.x = f2bf(o_[0]); h0.y = f2bf(o_[1]); h0.z = f2bf(o_[2]); h0.w = f2bf(o_[3]);
        h1.x = f2bf(o_[4]); h1.y = f2bf(o_[5]); h1.z = f2bf(o_[6]); h1.w = f2bf(o_[7]);
        *(ushort4*)ph       = h0;
        *(ushort4*)(ph + 4) = h1;
    }
}

__global__ __launch_bounds__(256)
void pos_k(float* __restrict__ pos, const float* __restrict__ lemb)
{
    const int q = blockIdx.x;
    const int d = threadIdx.x;
    int lvl, start, S;
    level_of(q, lvl, start, S);
    const int qi = q - start;
    const int r = qi / S, c = qi % S;
    const float twopi = 6.283185307179586f;
    float e; int dd;
    if (d < 128) { e = (float)(r + 1) / ((float)S + 1e-6f) * twopi; dd = d; }
    else         { e = (float)(c + 1) / ((float)S + 1e-6f) * twopi; dd = d - 128; }
    const float dimt = expf(9.210340371976184f * (float)(dd & ~1) / 128.f);
    const float p = e / dimt;
    const float v = (dd & 1) ? cosf(p) : sinf(p);
    pos[(long)q * DD + d] = v + lemb[lvl * DD + d];
}

__global__ __launch_bounds__(256)
void add_pos_bf_k(const float* __restrict__ src, const float* __restrict__ pos,
                  unsigned short* __restrict__ q)
{
    const long i = ((long)blockIdx.x * 256 + threadIdx.x) * 4;
    const long rem = i % (long)(LQT * DD);
    const float4 s = *(const float4*)(src + i);
    const float4 p = *(const float4*)(pos + rem);
    ushort4 o;
    o.x = f2bf(s.x + p.x); o.y = f2bf(s.y + p.y);
    o.z = f2bf(s.z + p.z); o.w = f2bf(s.w + p.w);
    *(ushort4*)(q + i) = o;
}

// ---------------------------------------------------------------------------
// Deformable attention v3: 2 queries/block; softmax fused in phase A;
// phase B gathers uint2 (4 bf16 channels) per corner.
// ---------------------------------------------------------------------------
__global__ __launch_bounds__(256)
void msdeform_k(const unsigned short* __restrict__ val,
                const unsigned short* __restrict__ off,
                const float* __restrict__ aw,
                unsigned short* __restrict__ out)
{
    __shared__ int   s_base[2][128][4];
    __shared__ float s_w[2][128][4];
    const int t = threadIdx.x;
    const int j = t >> 7;
    const int tt = t & 127;
    const int bq = blockIdx.x * 2 + j;
    const int b = bq / LQT, q = bq - b * LQT;
    int lvl0, start0, S0;
    level_of(q, lvl0, start0, S0);
    const int qi = q - start0;
    {
        const int lv = (tt >> 2) & 3;
        const int SL[4]  = {96, 48, 24, 12};
        const int STL[4] = {0, 9216, 11520, 12096};
        const int S = SL[lv];
        const float refx = ((float)(qi % S0) + 0.5f) / (float)S0;
        const float refy = ((float)(qi / S0) + 0.5f) / (float)S0;
        const unsigned int ou = *(const unsigned int*)(off + (long)bq * 256 + 2 * tt);
        const float x = refx * (float)S - 0.5f + bf2f((unsigned short)(ou & 0xffffu));
        const float y = refy * (float)S - 0.5f + bf2f((unsigned short)(ou >> 16));
        const float logit = aw[(long)bq * 128 + tt];
        float mx = logit;
        #pragma unroll
        for (int s_ = 1; s_ < 16; s_ <<= 1) mx = fmaxf(mx, __shfl_xor(mx, s_));
        const float e = __expf(logit - mx);
        float sum = e;
        #pragma unroll
        for (int s_ = 1; s_ < 16; s_ <<= 1) sum += __shfl_xor(sum, s_);
        const float wat = e / sum;
        const float x0 = floorf(x), y0 = floorf(y);
        const float tx = x - x0, ty = y - y0;
        const int ix = (int)x0, iy = (int)y0;
        #pragma unroll
        for (int c = 0; c < 4; ++c) {
            const int dx = c & 1, dy = c >> 1;
            const int xi = ix + dx, yi = iy + dy;
            const bool ok = (xi >= 0) && (xi < S) && (yi >= 0) && (yi < S);
            const int cx = min(max(xi, 0), S - 1);
            const int cy = min(max(yi, 0), S - 1);
            const float wxy = (dx ? tx : 1.f - tx) * (dy ? ty : 1.f - ty);
            s_base[j][tt][c] = (STL[lv] + cy * S + cx) * 256;
            s_w[j][tt][c] = ok ? wxy * wat : 0.f;
        }
    }
    __syncthreads();
    const int h = tt >> 4, d4 = (tt >> 1) & 7, sub = tt & 1;
    const unsigned short* vb = val + (long)b * (LQT * DD) + h * 32 + d4 * 4;
    float a0 = 0.f, a1 = 0.f, a2 = 0.f, a3 = 0.f;
    #pragma unroll
    for (int lp = 0; lp < 8; ++lp) {
        const int task = h * 16 + sub * 8 + lp;
        #pragma unroll
        for (int c = 0; c < 4; ++c) {
            const float wv = s_w[j][task][c];
            const uint2 g = *(const uint2*)(vb + s_base[j][task][c]);
            a0 = fmaf(wv, bf2f((unsigned short)(g.x & 0xffffu)), a0);
            a1 = fmaf(wv, bf2f((unsigned short)(g.x >> 16)), a1);
            a2 = fmaf(wv, bf2f((unsigned short)(g.y & 0xffffu)), a2);
            a3 = fmaf(wv, bf2f((unsigned short)(g.y >> 16)), a3);
        }
    }
    a0 += __shfl_xor(a0, 1);
    a1 += __shfl_xor(a1, 1);
    a2 += __shfl_xor(a2, 1);
    a3 += __shfl_xor(a3, 1);
    if (sub == 0) {
        ushort4 o;
        o.x = f2bf(a0); o.y = f2bf(a1); o.z = f2bf(a2); o.w = f2bf(a3);
        *(ushort4*)(out + (long)bq * DD + h * 32 + d4 * 4) = o;
    }
}

// LayerNorm over D=256; 4 rows/block, float4 per lane; writes f32 + bf16
__global__ __launch_bounds__(256)
void layernorm_k(const float* __restrict__ x, const float* __restrict__ g,
                 const float* __restrict__ b, float* __restrict__ outf,
                 unsigned short* __restrict__ outh)
{
    const int t = threadIdx.x;
    const long row = (long)blockIdx.x * 4 + (t >> 6);
    const int lane = t & 63;
    const float4 v = *(const float4*)(x + row * DD + lane * 4);
    float s  = v.x + v.y + v.z + v.w;
    float sq = v.x * v.x + v.y * v.y + v.z * v.z + v.w * v.w;
    #pragma unroll
    for (int o = 1; o < 64; o <<= 1) {
        s  += __shfl_xor(s, o);
        sq += __shfl_xor(sq, o);
    }
    const float mean = s * (1.f / 256.f);
    const float inv = rsqrtf(sq * (1.f / 256.f) - mean * mean + 1e-5f);
    const float4 gv = *(const float4*)(g + lane * 4);
    const float4 bv = *(const float4*)(b + lane * 4);
    float4 y;
    y.x = (v.x - mean) * inv * gv.x + bv.x;
    y.y = (v.y - mean) * inv * gv.y + bv.y;
    y.z = (v.z - mean) * inv * gv.z + bv.z;
    y.w = (v.w - mean) * inv * gv.w + bv.w;
    *(float4*)(outf + row * DD + lane * 4) = y;
    ushort4 hh;
    hh.x = f2bf(y.x); hh.y = f2bf(y.y); hh.z = f2bf(y.z); hh.w = f2bf(y.w);
    *(ushort4*)(outh + row * DD + lane * 4) = hh;
}

__global__ __launch_bounds__(256)
void cvt_k(const float* __restrict__ in, unsigned short* __restrict__ out, long n)
{
    const long i = ((long)blockIdx.x * 256 + threadIdx.x) * 4;
    if (i >= n) return;
    const float4 v = *(const float4*)(in + i);
    ushort4 o;
    o.x = f2bf(v.x); o.y = f2bf(v.y); o.z = f2bf(v.z); o.w = f2bf(v.w);
    *(ushort4*)(out + i) = o;
}

__global__ void tail_k(float* __restrict__ o)
{
    const float tv[28] = {0.f, 9216.f, 11520.f, 12096.f,
                          96.f, 96.f, 48.f, 48.f, 24.f, 24.f, 12.f, 12.f,
                          1.f, 1.f, 1.f, 1.f, 1.f, 1.f, 1.f, 1.f,
                          1.f, 1.f, 1.f, 1.f, 1.f, 1.f, 1.f, 1.f};
    const int t = threadIdx.x;
    if (t < 28) o[t] = tv[t];
}

extern "C" void kernel_launch(void* const* d_in, const int* in_sizes, int n_in,
                              void* d_out, int out_size, void* d_ws, size_t ws_size,
                              hipStream_t stream)
{
    const float* xs[4]  = {(const float*)d_in[0], (const float*)d_in[3],
                           (const float*)d_in[6], (const float*)d_in[9]};
    const float* fcw[4] = {(const float*)d_in[1], (const float*)d_in[4],
                           (const float*)d_in[7], (const float*)d_in[10]};
    const float* fcb[4] = {(const float*)d_in[2], (const float*)d_in[5],
                           (const float*)d_in[8], (const float*)d_in[11]};
    const float* gn_g = (const float*)d_in[12];
    const float* gn_b = (const float*)d_in[13];
    const float* lemb = (const float*)d_in[14];
    const float* off_w = (const float*)d_in[15];
    const float* off_b = (const float*)d_in[16];
    const float* aw_w  = (const float*)d_in[17];
    const float* aw_b  = (const float*)d_in[18];
    const float* val_w = (const float*)d_in[19];
    const float* val_b = (const float*)d_in[20];
    const float* out_w = (const float*)d_in[21];
    const float* out_b = (const float*)d_in[22];
    const float* ln1_g = (const float*)d_in[23];
    const float* ln1_b = (const float*)d_in[24];
    const float* l1_w  = (const float*)d_in[25];
    const float* l1_b  = (const float*)d_in[26];
    const float* l2_w  = (const float*)d_in[27];
    const float* l2_b  = (const float*)d_in[28];
    const float* ln2_g = (const float*)d_in[29];
    const float* ln2_b = (const float*)d_in[30];

    float* src = (float*)d_out;                 // (B, LQ, D)
    float* ws = (float*)d_ws;
    float* pos = ws;                            // 3,133,440 f32
    float* awb = pos + 3133440;                 // 3,133,440 f32 (raw logits)
    float* tmp = awb + 3133440;                 // 6,266,880 f32 (xt aliased at start)
    unsigned short* xt = (unsigned short*)tmp;  // 8,257,536 shorts used
    unsigned short* q_bf   = (unsigned short*)(tmp + 6266880);
    unsigned short* off_bf = q_bf   + 6266880;
    unsigned short* val_bf = off_bf + 6266880;
    unsigned short* msd_bf = val_bf + 6266880;
    unsigned short* hid_bf = q_bf;              // aliases q/off/val/msd: 25,067,520 shorts
    unsigned short* src_bf = msd_bf + 6266880;
    unsigned short* wb     = src_bf + 6266880;
    unsigned short* wb_fc[4];
    wb_fc[0] = wb;                              // 65536
    wb_fc[1] = wb_fc[0] + 65536;                // 131072
    wb_fc[2] = wb_fc[1] + 131072;               // 196608
    wb_fc[3] = wb_fc[2] + 196608;               // 262144
    unsigned short* wb_off = wb_fc[3] + 262144; // 6*65536
    unsigned short* wb_aw  = wb_off + 393216;   // 6*32768
    unsigned short* wb_val = wb_aw  + 196608;   // 6*65536
    unsigned short* wb_out = wb_val + 393216;   // 6*65536
    unsigned short* wb_l1  = wb_out + 393216;   // 6*262144
    unsigned short* wb_l2  = wb_l1  + 1572864;  // 6*262144
    (void)in_sizes; (void)n_in; (void)out_size; (void)ws_size;

    const int CINS[4]   = {256, 512, 768, 1024};
    const int SS[4]     = {96, 48, 24, 12};
    const int STARTS[4] = {0, 9216, 11520, 12096};
    const long XTOFF[4] = {0, 4718592, 7077888, 7962624};

    // 0) weights -> bf16
    cvt_k<<<64,   256, 0, stream>>>(fcw[0], wb_fc[0], 65536);
    cvt_k<<<128,  256, 0, stream>>>(fcw[1], wb_fc[1], 131072);
    cvt_k<<<192,  256, 0, stream>>>(fcw[2], wb_fc[2], 196608);
    cvt_k<<<256,  256, 0, stream>>>(fcw[3], wb_fc[3], 262144);
    cvt_k<<<384,  256, 0, stream>>>(off_w, wb_off, 393216);
    cvt_k<<<192,  256, 0, stream>>>(aw_w,  wb_aw,  196608);
    cvt_k<<<384,  256, 0, stream>>>(val_w, wb_val, 393216);
    cvt_k<<<384,  256, 0, stream>>>(out_w, wb_out, 393216);
    cvt_k<<<1536, 256, 0, stream>>>(l1_w,  wb_l1,  1572864);
    cvt_k<<<1536, 256, 0, stream>>>(l2_w,  wb_l2,  1572864);

    // 1) transpose inputs + bf16 projections
    for (int i = 0; i < 4; ++i) {
        const int Ml = SS[i] * SS[i];
        tp_k<<<dim3((Ml + 31) / 32, CINS[i] / 32, BB), 256, 0, stream>>>(
            xs[i], xt + XTOFF[i], CINS[i], Ml);
    }
    for (int i = 0; i < 4; ++i) {
        const int Ml = SS[i] * SS[i];
        gemm64<<<dim3((Ml + 63) / 64, 2, BB), 256, 0, stream>>>(
            xt + XTOFF[i], (long)Ml * CINS[i],
            wb_fc[i], nullptr, fcb[i], nullptr, nullptr,
            src + (long)STARTS[i] * DD, (long)LQT * DD, nullptr,
            Ml, DD, CINS[i], 0);
    }
    // 2) group norm -> src (f32) + src_bf
    groupnorm_k<<<dim3(32, 4, BB), 256, 0, stream>>>(src, src_bf, gn_g, gn_b);
    // 3) positional embedding
    pos_k<<<LQT, 256, 0, stream>>>(pos, lemb);

    // 4) encoder layers
    for (int l = 0; l < 6; ++l) {
        add_pos_bf_k<<<6120, 256, 0, stream>>>(src, pos, q_bf);
        // merged off(256) + aw(128) projection, N=384
        gemm64<<<dim3(383, 3, 1), 256, 0, stream>>>(
            q_bf, 0, wb_off + (long)l * 65536, wb_aw + (long)l * 32768,
            off_b + l * DD, aw_b + l * 128, nullptr,
            awb, 0, off_bf, MROWS, 384, DD, 4);
        gemm64<<<dim3(383, 2, 1), 256, 0, stream>>>(
            src_bf, 0, wb_val + (long)l * 65536, nullptr,
            val_b + l * DD, nullptr, nullptr,
            nullptr, 0, val_bf, MROWS, DD, DD, 3);
        msdeform_k<<<MROWS / 2, 256, 0, stream>>>(val_bf, off_bf, awb, msd_bf);
        gemm64<<<dim3(383, 2, 1), 256, 0, stream>>>(
            msd_bf, 0, wb_out + (long)l * 65536, nullptr,
            out_b + l * DD, nullptr, src,
            tmp, 0, nullptr, MROWS, DD, DD, 2);
        layernorm_k<<<MROWS / 4, 256, 0, stream>>>(
            tmp, ln1_g + l * DD, ln1_b + l * DD, src, src_bf);
        gemm128<<<dim3(192, 8, 1), 256, 0, stream>>>(
            src_bf, wb_l1 + (long)l * 262144, l1_b + l * DFFN, hid_bf,
            MROWS, DFFN, DD);
        gemm64<<<dim3(383, 2, 1), 256, 0, stream>>>(
            hid_bf, 0, wb_l2 + (long)l * 262144, nullptr,
            l2_b + l * DD, nullptr, src,
            tmp, 0, nullptr, MROWS, DD, DFFN, 2);
        layernorm_k<<<MROWS / 4, 256, 0, stream>>>(
            tmp, ln2_g + l * DD, ln2_b + l * DD, src, src_bf);
    }
    // 5) constant tail outputs
    tail_k<<<1, 32, 0, stream>>>(src + (long)BB * LQT * DD);
}

// Round 4
// 1771.972 us; speedup vs baseline: 3.9606x; 1.1596x over previous
//
#include <hip/hip_runtime.h>
#include <math.h>

#define DD 256
#define DFFN 1024
#define LQT 12240
#define BB 2
#define MROWS (BB * LQT)   // 24480

typedef __attribute__((ext_vector_type(8))) short short8v;
typedef __attribute__((ext_vector_type(4))) float floatx4;

__device__ __forceinline__ unsigned short f2bf(float x) {
    unsigned int u = __builtin_bit_cast(unsigned int, x);
    u = (u + 0x7fffu + ((u >> 16) & 1u)) >> 16;
    return (unsigned short)u;
}
__device__ __forceinline__ float bf2f(unsigned short h) {
    unsigned int u = ((unsigned int)h) << 16;
    return __builtin_bit_cast(float, u);
}

__device__ __forceinline__ void gload16(const unsigned short* g, unsigned short* lds) {
    __builtin_amdgcn_global_load_lds(
        (const __attribute__((address_space(1))) unsigned int*)g,
        (__attribute__((address_space(3))) unsigned int*)lds, 16, 0, 0);
}

__device__ __forceinline__ void level_of(int q, int& lvl, int& start, int& S) {
    if (q < 9216)       { lvl = 0; start = 0;     S = 96; }
    else if (q < 11520) { lvl = 1; start = 9216;  S = 48; }
    else if (q < 12096) { lvl = 2; start = 11520; S = 24; }
    else                { lvl = 3; start = 12096; S = 12; }
}

// ---------------------------------------------------------------------------
// BM=64 x BN=128 bf16 MFMA GEMM, double-buffered global_load_lds staging.
// op: 0 = f32 out (+z batching); 2 = +R f32 out; 3 = bf16 out;
//     4 = merged off/aw: n0<256 -> Ch (stride 256); n0>=256 -> Cf (stride 128, W2/bias2)
// ---------------------------------------------------------------------------
__global__ __launch_bounds__(256)
void gemm64(const unsigned short* __restrict__ A, long aZ,
            const unsigned short* __restrict__ W,
            const unsigned short* __restrict__ W2,
            const float* __restrict__ bias, const float* __restrict__ bias2,
            const float* __restrict__ R,
            float* __restrict__ Cf, long cZ, unsigned short* __restrict__ Ch,
            int M, int N, int K, int op)
{
    __shared__ alignas(16) unsigned short As[2][4][64][8];
    __shared__ alignas(16) unsigned short Bs[2][4][128][8];
    const int t = threadIdx.x;
    const int z = blockIdx.z;
    A  += (long)z * aZ;
    if (Cf) Cf += (long)z * cZ;
    const int m0 = blockIdx.x * 64;
    const int n0 = blockIdx.y * 128;
    const int wv = __builtin_amdgcn_readfirstlane(t >> 6);
    const int lane = t & 63;
    const int wm = wv >> 1, wn = wv & 1;
    const int kb = lane >> 4, lr = lane & 15;

    const unsigned short* Wb = W;
    const float* bi = bias;
    int nb = n0;
    if (op == 4 && n0 >= 256) { Wb = W2; bi = bias2; nb = n0 - 256; }

    const int ar = min(m0 + lane, M - 1);
    const unsigned short* gA  = A  + (long)ar * K + wv * 8;
    const unsigned short* gB0 = Wb + (long)(nb + lane) * K + wv * 8;
    const unsigned short* gB1 = Wb + (long)(nb + 64 + lane) * K + wv * 8;

    floatx4 acc[2][4];
    #pragma unroll
    for (int m = 0; m < 2; ++m)
        #pragma unroll
        for (int n = 0; n < 4; ++n)
            acc[m][n] = (floatx4){0.f, 0.f, 0.f, 0.f};

    // prologue: stage tile 0 into buffer 0
    gload16(gA,  &As[0][wv][0][0]);
    gload16(gB0, &Bs[0][wv][0][0]);
    gload16(gB1, &Bs[0][wv][64][0]);
    gA += 32; gB0 += 32; gB1 += 32;
    __syncthreads();

    const int nk = K >> 5;
    for (int kt = 0; kt < nk; ++kt) {
        const int cur = kt & 1;
        if (kt + 1 < nk) {
            gload16(gA,  &As[cur ^ 1][wv][0][0]);
            gload16(gB0, &Bs[cur ^ 1][wv][0][0]);
            gload16(gB1, &Bs[cur ^ 1][wv][64][0]);
            gA += 32; gB0 += 32; gB1 += 32;
        }
        short8v av[2], bv[4];
        #pragma unroll
        for (int m = 0; m < 2; ++m)
            av[m] = *(const short8v*)&As[cur][kb][wm * 32 + m * 16 + lr][0];
        #pragma unroll
        for (int n = 0; n < 4; ++n)
            bv[n] = *(const short8v*)&Bs[cur][kb][wn * 64 + n * 16 + lr][0];
        #pragma unroll
        for (int m = 0; m < 2; ++m)
            #pragma unroll
            for (int n = 0; n < 4; ++n)
                acc[m][n] = __builtin_amdgcn_mfma_f32_16x16x32_bf16(
                    av[m], bv[n], acc[m][n], 0, 0, 0);
        __syncthreads();
    }

    const int lh = lane >> 4;
    #pragma unroll
    for (int m = 0; m < 2; ++m) {
        const int row0 = m0 + wm * 32 + m * 16 + lh * 4;
        #pragma unroll
        for (int n = 0; n < 4; ++n) {
            const int col = n0 + wn * 64 + n * 16 + lr;
            #pragma unroll
            for (int r = 0; r < 4; ++r) {
                const int row = row0 + r;
                if (row >= M) continue;
                float v = acc[m][n][r];
                if (op == 4) {
                    if (n0 < 256) Ch[(long)row * 256 + col] = f2bf(v + bi[col]);
                    else          Cf[(long)row * 128 + (col - 256)] = v + bi[col - 256];
                } else {
                    v += bias[col];
                    const long o = (long)row * N + col;
                    if (op == 0)      Cf[o] = v;
                    else if (op == 2) Cf[o] = v + R[o];
                    else              Ch[o] = f2bf(v);
                }
            }
        }
    }
}

// ---------------------------------------------------------------------------
// BM=128 x BN=128 variant for FFN1 (relu -> bf16 out), double-buffered
// ---------------------------------------------------------------------------
__global__ __launch_bounds__(256)
void gemm128(const unsigned short* __restrict__ A,
             const unsigned short* __restrict__ W,
             const float* __restrict__ bias, unsigned short* __restrict__ Ch,
             int M, int N, int K)
{
    __shared__ alignas(16) unsigned short As[2][4][128][8];
    __shared__ alignas(16) unsigned short Bs[2][4][128][8];
    const int t = threadIdx.x;
    const int m0 = blockIdx.x * 128;
    const int n0 = blockIdx.y * 128;
    const int wv = __builtin_amdgcn_readfirstlane(t >> 6);
    const int lane = t & 63;
    const int wm = wv >> 1, wn = wv & 1;
    const int kb = lane >> 4, lr = lane & 15;

    const int r0 = min(m0 + lane, M - 1);
    const int r1 = min(m0 + 64 + lane, M - 1);
    const unsigned short* gA0 = A + (long)r0 * K + wv * 8;
    const unsigned short* gA1 = A + (long)r1 * K + wv * 8;
    const unsigned short* gB0 = W + (long)(n0 + lane) * K + wv * 8;
    const unsigned short* gB1 = W + (long)(n0 + 64 + lane) * K + wv * 8;

    floatx4 acc[4][4];
    #pragma unroll
    for (int m = 0; m < 4; ++m)
        #pragma unroll
        for (int n = 0; n < 4; ++n)
            acc[m][n] = (floatx4){0.f, 0.f, 0.f, 0.f};

    gload16(gA0, &As[0][wv][0][0]);
    gload16(gA1, &As[0][wv][64][0]);
    gload16(gB0, &Bs[0][wv][0][0]);
    gload16(gB1, &Bs[0][wv][64][0]);
    gA0 += 32; gA1 += 32; gB0 += 32; gB1 += 32;
    __syncthreads();

    const int nk = K >> 5;
    for (int kt = 0; kt < nk; ++kt) {
        const int cur = kt & 1;
        if (kt + 1 < nk) {
            gload16(gA0, &As[cur ^ 1][wv][0][0]);
            gload16(gA1, &As[cur ^ 1][wv][64][0]);
            gload16(gB0, &Bs[cur ^ 1][wv][0][0]);
            gload16(gB1, &Bs[cur ^ 1][wv][64][0]);
            gA0 += 32; gA1 += 32; gB0 += 32; gB1 += 32;
        }
        short8v av[4], bv[4];
        #pragma unroll
        for (int m = 0; m < 4; ++m)
            av[m] = *(const short8v*)&As[cur][kb][wm * 64 + m * 16 + lr][0];
        #pragma unroll
        for (int n = 0; n < 4; ++n)
            bv[n] = *(const short8v*)&Bs[cur][kb][wn * 64 + n * 16 + lr][0];
        #pragma unroll
        for (int m = 0; m < 4; ++m)
            #pragma unroll
            for (int n = 0; n < 4; ++n)
                acc[m][n] = __builtin_amdgcn_mfma_f32_16x16x32_bf16(
                    av[m], bv[n], acc[m][n], 0, 0, 0);
        __syncthreads();
    }

    const int lh = lane >> 4;
    #pragma unroll
    for (int m = 0; m < 4; ++m) {
        const int row0 = m0 + wm * 64 + m * 16 + lh * 4;
        #pragma unroll
        for (int n = 0; n < 4; ++n) {
            const int col = n0 + wn * 64 + n * 16 + lr;
            const float b = bias[col];
            #pragma unroll
            for (int r = 0; r < 4; ++r) {
                const int row = row0 + r;
                if (row >= M) continue;
                Ch[(long)row * N + col] = f2bf(fmaxf(acc[m][n][r] + b, 0.f));
            }
        }
    }
}

// ---------------------------------------------------------------------------
// transpose (C, Ml) f32 -> (Ml, C) bf16, batch via blockIdx.z
// ---------------------------------------------------------------------------
__global__ __launch_bounds__(256)
void tp_k(const float* __restrict__ x, unsigned short* __restrict__ xt,
          int C, int Ml)
{
    __shared__ float tile[32][33];
    const int m0 = blockIdx.x * 32, c0 = blockIdx.y * 32;
    const int zb = blockIdx.z;
    const float* px = x + (long)zb * C * Ml;
    unsigned short* pxt = xt + (long)zb * Ml * C;
    const int t = threadIdx.x;
    {
        const int cl = t >> 3, m4 = (t & 7) * 4;
        const int gm = m0 + m4;
        if (gm < Ml) {
            const float4 v = *(const float4*)(px + (long)(c0 + cl) * Ml + gm);
            tile[cl][m4 + 0] = v.x; tile[cl][m4 + 1] = v.y;
            tile[cl][m4 + 2] = v.z; tile[cl][m4 + 3] = v.w;
        }
    }
    __syncthreads();
    {
        const int ml = t >> 3, c4 = (t & 7) * 4;
        const int gm = m0 + ml;
        if (gm < Ml) {
            ushort4 o;
            o.x = f2bf(tile[c4 + 0][ml]);
            o.y = f2bf(tile[c4 + 1][ml]);
            o.z = f2bf(tile[c4 + 2][ml]);
            o.w = f2bf(tile[c4 + 3][ml]);
            *(ushort4*)(pxt + (long)gm * C + c0 + c4) = o;
        }
    }
}

// ---------------------------------------------------------------------------
// GroupNorm phase 1: per-(batch,chunk) partial sums. 256 blocks.
// chunk map: lvl0 96 chunks x 96 rows, lvl1 24x96, lvl2 6x96, lvl3 2x72
// ---------------------------------------------------------------------------
__global__ __launch_bounds__(256)
void gn_part(const float* __restrict__ src, float* __restrict__ part)
{
    const int x = blockIdx.x;
    const int b = x >> 7, c = x & 127;
    int lvl, chunk;
    if (c < 96)       { lvl = 0; chunk = c; }
    else if (c < 120) { lvl = 1; chunk = c - 96; }
    else if (c < 126) { lvl = 2; chunk = c - 120; }
    else              { lvl = 3; chunk = c - 126; }
    const int starts[4] = {0, 9216, 11520, 12096};
    const int crows[4]  = {96, 96, 96, 72};
    const int rows = crows[lvl];
    const long base = ((long)b * LQT + starts[lvl] + (long)chunk * rows) * DD;
    const int t = threadIdx.x;
    float s = 0.f, sq = 0.f;
    for (int r = 0; r < rows; ++r) {
        const float v = src[base + (long)r * DD + t];
        s += v; sq += v * v;
    }
    #pragma unroll
    for (int o = 1; o < 8; o <<= 1) {
        s  += __shfl_xor(s, o);
        sq += __shfl_xor(sq, o);
    }
    if ((t & 7) == 0) {
        float* p = part + ((long)x * 32 + (t >> 3)) * 2;
        p[0] = s; p[1] = sq;
    }
}

// GroupNorm phase 2: finalize 256 (b,lvl,grp) stats
__global__ void gn_fin(const float* __restrict__ part, float* __restrict__ stat)
{
    const int t = threadIdx.x;
    const int b = t >> 7, rest = t & 127;
    const int lvl = rest >> 5, grp = rest & 31;
    const int cbase[4] = {0, 96, 120, 126};
    const int ccnt[4]  = {96, 24, 6, 2};
    const int Ml[4]    = {9216, 2304, 576, 144};
    float s = 0.f, sq = 0.f;
    for (int i = 0; i < ccnt[lvl]; ++i) {
        const float* p = part + ((long)(b * 128 + cbase[lvl] + i) * 32 + grp) * 2;
        s += p[0]; sq += p[1];
    }
    const float cnt = (float)(Ml[lvl] * 8);
    const float mean = s / cnt;
    const float inv = rsqrtf(sq / cnt - mean * mean + 1e-5f);
    float* o = stat + ((b * 4 + lvl) * 32 + grp) * 2;
    o[0] = mean; o[1] = inv;
}

// GroupNorm phase 3: apply; writes src f32, src_bf, and q_bf = bf16(y+pos)
__global__ __launch_bounds__(256)
void gn_apply(float* __restrict__ src, unsigned short* __restrict__ srch,
              unsigned short* __restrict__ qout,
              const float* __restrict__ stat,
              const float* __restrict__ gg, const float* __restrict__ gb,
              const float* __restrict__ pos)
{
    const int t = threadIdx.x;
    const long row = (long)blockIdx.x * 4 + (t >> 6);
    const int lane = t & 63;
    const int b = row >= LQT;
    const int q = (int)row - b * LQT;
    int lvl, start, S;
    level_of(q, lvl, start, S);
    const float2 ms = *(const float2*)(stat + ((b * 4 + lvl) * 32 + (lane >> 1)) * 2);
    const int col = lane * 4;
    const float4 v  = *(const float4*)(src + row * DD + col);
    const float4 gv = *(const float4*)(gg + lvl * DD + col);
    const float4 bv = *(const float4*)(gb + lvl * DD + col);
    float4 y;
    y.x = (v.x - ms.x) * ms.y * gv.x + bv.x;
    y.y = (v.y - ms.x) * ms.y * gv.y + bv.y;
    y.z = (v.z - ms.x) * ms.y * gv.z + bv.z;
    y.w = (v.w - ms.x) * ms.y * gv.w + bv.w;
    *(float4*)(src + row * DD + col) = y;
    ushort4 hh;
    hh.x = f2bf(y.x); hh.y = f2bf(y.y); hh.z = f2bf(y.z); hh.w = f2bf(y.w);
    *(ushort4*)(srch + row * DD + col) = hh;
    const float4 pv = *(const float4*)(pos + (long)q * DD + col);
    ushort4 qq;
    qq.x = f2bf(y.x + pv.x); qq.y = f2bf(y.y + pv.y);
    qq.z = f2bf(y.z + pv.z); qq.w = f2bf(y.w + pv.w);
    *(ushort4*)(qout + row * DD + col) = qq;
}

__global__ __launch_bounds__(256)
void pos_k(float* __restrict__ pos, const float* __restrict__ lemb)
{
    const int q = blockIdx.x;
    const int d = threadIdx.x;
    int lvl, start, S;
    level_of(q, lvl, start, S);
    const int qi = q - start;
    const int r = qi / S, c = qi % S;
    const float twopi = 6.283185307179586f;
    float e; int dd;
    if (d < 128) { e = (float)(r + 1) / ((float)S + 1e-6f) * twopi; dd = d; }
    else         { e = (float)(c + 1) / ((float)S + 1e-6f) * twopi; dd = d - 128; }
    const float dimt = expf(9.210340371976184f * (float)(dd & ~1) / 128.f);
    const float p = e / dimt;
    const float v = (dd & 1) ? cosf(p) : sinf(p);
    pos[(long)q * DD + d] = v + lemb[lvl * DD + d];
}

// ---------------------------------------------------------------------------
// Deformable attention v4: 2 queries/block; softmax fused in phase A;
// phase B: thread=(h,d8,sub) gathers uint4 (8 bf16 ch), 16 loads/thread.
// ---------------------------------------------------------------------------
__global__ __launch_bounds__(256)
void msdeform_k(const unsigned short* __restrict__ val,
                const unsigned short* __restrict__ off,
                const float* __restrict__ aw,
                unsigned short* __restrict__ out)
{
    __shared__ int   s_base[2][128][4];
    __shared__ float s_w[2][128][4];
    const int t = threadIdx.x;
    const int j = t >> 7;
    const int tt = t & 127;
    const int bq = blockIdx.x * 2 + j;
    const int b = bq >= LQT;
    const int q = bq - b * LQT;
    int lvl0, start0, S0;
    level_of(q, lvl0, start0, S0);
    const int qi = q - start0;
    {
        const int lv = (tt >> 2) & 3;
        const int SL[4]  = {96, 48, 24, 12};
        const int STL[4] = {0, 9216, 11520, 12096};
        const int S = SL[lv];
        const float refx = ((float)(qi % S0) + 0.5f) / (float)S0;
        const float refy = ((float)(qi / S0) + 0.5f) / (float)S0;
        const unsigned int ou = *(const unsigned int*)(off + (long)bq * 256 + 2 * tt);
        const float x = refx * (float)S - 0.5f + bf2f((unsigned short)(ou & 0xffffu));
        const float y = refy * (float)S - 0.5f + bf2f((unsigned short)(ou >> 16));
        const float logit = aw[(long)bq * 128 + tt];
        float mx = logit;
        #pragma unroll
        for (int s_ = 1; s_ < 16; s_ <<= 1) mx = fmaxf(mx, __shfl_xor(mx, s_));
        const float e = __expf(logit - mx);
        float sum = e;
        #pragma unroll
        for (int s_ = 1; s_ < 16; s_ <<= 1) sum += __shfl_xor(sum, s_);
        const float wat = e / sum;
        const float x0 = floorf(x), y0 = floorf(y);
        const float tx = x - x0, ty = y - y0;
        const int ix = (int)x0, iy = (int)y0;
        #pragma unroll
        for (int c = 0; c < 4; ++c) {
            const int dx = c & 1, dy = c >> 1;
            const int xi = ix + dx, yi = iy + dy;
            const bool ok = (xi >= 0) && (xi < S) && (yi >= 0) && (yi < S);
            const int cx = min(max(xi, 0), S - 1);
            const int cy = min(max(yi, 0), S - 1);
            const float wxy = (dx ? tx : 1.f - tx) * (dy ? ty : 1.f - ty);
            s_base[j][tt][c] = (STL[lv] + cy * S + cx) * 256;
            s_w[j][tt][c] = ok ? wxy * wat : 0.f;
        }
    }
    __syncthreads();
    const int h = tt >> 4, d8 = (tt >> 2) & 3, sub = tt & 3;
    const unsigned short* vb = val + (long)b * (LQT * DD) + h * 32 + d8 * 8;
    float a0 = 0.f, a1 = 0.f, a2 = 0.f, a3 = 0.f;
    float a4 = 0.f, a5 = 0.f, a6 = 0.f, a7 = 0.f;
    #pragma unroll
    for (int i = 0; i < 4; ++i) {
        const int task = h * 16 + i * 4 + sub;
        #pragma unroll
        for (int c = 0; c < 4; ++c) {
            const float wv = s_w[j][task][c];
            const uint4 g = *(const uint4*)(vb + s_base[j][task][c]);
            a0 = fmaf(wv, bf2f((unsigned short)(g.x & 0xffffu)), a0);
            a1 = fmaf(wv, bf2f((unsigned short)(g.x >> 16)), a1);
            a2 = fmaf(wv, bf2f((unsigned short)(g.y & 0xffffu)), a2);
            a3 = fmaf(wv, bf2f((unsigned short)(g.y >> 16)), a3);
            a4 = fmaf(wv, bf2f((unsigned short)(g.z & 0xffffu)), a4);
            a5 = fmaf(wv, bf2f((unsigned short)(g.z >> 16)), a5);
            a6 = fmaf(wv, bf2f((unsigned short)(g.w & 0xffffu)), a6);
            a7 = fmaf(wv, bf2f((unsigned short)(g.w >> 16)), a7);
        }
    }
    #pragma unroll
    for (int o = 1; o < 4; o <<= 1) {
        a0 += __shfl_xor(a0, o); a1 += __shfl_xor(a1, o);
        a2 += __shfl_xor(a2, o); a3 += __shfl_xor(a3, o);
        a4 += __shfl_xor(a4, o); a5 += __shfl_xor(a5, o);
        a6 += __shfl_xor(a6, o); a7 += __shfl_xor(a7, o);
    }
    if (sub == 0) {
        uint4 o;
        o.x = (unsigned)f2bf(a0) | ((unsigned)f2bf(a1) << 16);
        o.y = (unsigned)f2bf(a2) | ((unsigned)f2bf(a3) << 16);
        o.z = (unsigned)f2bf(a4) | ((unsigned)f2bf(a5) << 16);
        o.w = (unsigned)f2bf(a6) | ((unsigned)f2bf(a7) << 16);
        *(uint4*)(out + (long)bq * DD + h * 32 + d8 * 8) = o;
    }
}

// LayerNorm over D=256; 4 rows/block; writes f32 + bf16 (+ optional q=bf16(y+pos))
__global__ __launch_bounds__(256)
void layernorm_k(const float* __restrict__ x, const float* __restrict__ g,
                 const float* __restrict__ b, float* __restrict__ outf,
                 unsigned short* __restrict__ outh,
                 const float* __restrict__ pos, unsigned short* __restrict__ qout)
{
    const int t = threadIdx.x;
    const long row = (long)blockIdx.x * 4 + (t >> 6);
    const int lane = t & 63;
    const float4 v = *(const float4*)(x + row * DD + lane * 4);
    float s  = v.x + v.y + v.z + v.w;
    float sq = v.x * v.x + v.y * v.y + v.z * v.z + v.w * v.w;
    #pragma unroll
    for (int o = 1; o < 64; o <<= 1) {
        s  += __shfl_xor(s, o);
        sq += __shfl_xor(sq, o);
    }
    const float mean = s * (1.f / 256.f);
    const float inv = rsqrtf(sq * (1.f / 256.f) - mean * mean + 1e-5f);
    const float4 gv = *(const float4*)(g + lane * 4);
    const float4 bv = *(const float4*)(b + lane * 4);
    float4 y;
    y.x = (v.x - mean) * inv * gv.x + bv.x;
    y.y = (v.y - mean) * inv * gv.y + bv.y;
    y.z = (v.z - mean) * inv * gv.z + bv.z;
    y.w = (v.w - mean) * inv * gv.w + bv.w;
    *(float4*)(outf + row * DD + lane * 4) = y;
    ushort4 hh;
    hh.x = f2bf(y.x); hh.y = f2bf(y.y); hh.z = f2bf(y.z); hh.w = f2bf(y.w);
    *(ushort4*)(outh + row * DD + lane * 4) = hh;
    if (qout) {
        const int qrow = (int)row - (row >= LQT ? LQT : 0);
        const float4 pv = *(const float4*)(pos + (long)qrow * DD + lane * 4);
        ushort4 qq;
        qq.x = f2bf(y.x + pv.x); qq.y = f2bf(y.y + pv.y);
        qq.z = f2bf(y.z + pv.z); qq.w = f2bf(y.w + pv.w);
        *(ushort4*)(qout + row * DD + lane * 4) = qq;
    }
}

__global__ __launch_bounds__(256)
void cvt_k(const float* __restrict__ in, unsigned short* __restrict__ out, long n)
{
    const long i = ((long)blockIdx.x * 256 + threadIdx.x) * 4;
    if (i >= n) return;
    const float4 v = *(const float4*)(in + i);
    ushort4 o;
    o.x = f2bf(v.x); o.y = f2bf(v.y); o.z = f2bf(v.z); o.w = f2bf(v.w);
    *(ushort4*)(out + i) = o;
}

__global__ void tail_k(float* __restrict__ o)
{
    const float tv[28] = {0.f, 9216.f, 11520.f, 12096.f,
                          96.f, 96.f, 48.f, 48.f, 24.f, 24.f, 12.f, 12.f,
                          1.f, 1.f, 1.f, 1.f, 1.f, 1.f, 1.f, 1.f,
                          1.f, 1.f, 1.f, 1.f, 1.f, 1.f, 1.f, 1.f};
    const int t = threadIdx.x;
    if (t < 28) o[t] = tv[t];
}

extern "C" void kernel_launch(void* const* d_in, const int* in_sizes, int n_in,
                              void* d_out, int out_size, void* d_ws, size_t ws_size,
                              hipStream_t stream)
{
    const float* xs[4]  = {(const float*)d_in[0], (const float*)d_in[3],
                           (const float*)d_in[6], (const float*)d_in[9]};
    const float* fcw[4] = {(const float*)d_in[1], (const float*)d_in[4],
                           (const float*)d_in[7], (const float*)d_in[10]};
    const float* fcb[4] = {(const float*)d_in[2], (const float*)d_in[5],
                           (const float*)d_in[8], (const float*)d_in[11]};
    const float* gn_g = (const float*)d_in[12];
    const float* gn_b = (const float*)d_in[13];
    const float* lemb = (const float*)d_in[14];
    const float* off_w = (const float*)d_in[15];
    const float* off_b = (const float*)d_in[16];
    const float* aw_w  = (const float*)d_in[17];
    const float* aw_b  = (const float*)d_in[18];
    const float* val_w = (const float*)d_in[19];
    const float* val_b = (const float*)d_in[20];
    const float* out_w = (const float*)d_in[21];
    const float* out_b = (const float*)d_in[22];
    const float* ln1_g = (const float*)d_in[23];
    const float* ln1_b = (const float*)d_in[24];
    const float* l1_w  = (const float*)d_in[25];
    const float* l1_b  = (const float*)d_in[26];
    const float* l2_w  = (const float*)d_in[27];
    const float* l2_b  = (const float*)d_in[28];
    const float* ln2_g = (const float*)d_in[29];
    const float* ln2_b = (const float*)d_in[30];

    float* src = (float*)d_out;                 // (B, LQ, D)
    float* ws = (float*)d_ws;
    float* pos = ws;                            // 3,133,440 f32
    float* awb = pos + 3133440;                 // 3,133,440 f32 (aw logits)
    float* tmp = awb + 3133440;                 // 6,266,880 f32 (xt aliased at start)
    unsigned short* xt = (unsigned short*)tmp;
    unsigned short* q_bf   = (unsigned short*)(tmp + 6266880);
    unsigned short* off_bf = q_bf   + 6266880;
    unsigned short* val_bf = off_bf + 6266880;
    unsigned short* msd_bf = val_bf + 6266880;
    unsigned short* hid_bf = q_bf;              // aliases q/off/val/msd (FFN hidden)
    unsigned short* src_bf = msd_bf + 6266880;
    unsigned short* wb     = src_bf + 6266880;
    unsigned short* wb_fc[4];
    wb_fc[0] = wb;
    wb_fc[1] = wb_fc[0] + 65536;
    wb_fc[2] = wb_fc[1] + 131072;
    wb_fc[3] = wb_fc[2] + 196608;
    unsigned short* wb_off = wb_fc[3] + 262144;
    unsigned short* wb_aw  = wb_off + 393216;
    unsigned short* wb_val = wb_aw  + 196608;
    unsigned short* wb_out = wb_val + 393216;
    unsigned short* wb_l1  = wb_out + 393216;
    unsigned short* wb_l2  = wb_l1  + 1572864;
    float* part = (float*)(wb_l2 + 1572864);    // 16384 f32
    float* stat = part + 16384;                 // 512 f32
    (void)in_sizes; (void)n_in; (void)out_size; (void)ws_size;

    const int CINS[4]   = {256, 512, 768, 1024};
    const int SS[4]     = {96, 48, 24, 12};
    const int STARTS[4] = {0, 9216, 11520, 12096};
    const long XTOFF[4] = {0, 4718592, 7077888, 7962624};

    // 0) weights -> bf16; positional embedding (needed by gn_apply)
    pos_k<<<LQT, 256, 0, stream>>>(pos, lemb);
    cvt_k<<<64,   256, 0, stream>>>(fcw[0], wb_fc[0], 65536);
    cvt_k<<<128,  256, 0, stream>>>(fcw[1], wb_fc[1], 131072);
    cvt_k<<<192,  256, 0, stream>>>(fcw[2], wb_fc[2], 196608);
    cvt_k<<<256,  256, 0, stream>>>(fcw[3], wb_fc[3], 262144);
    cvt_k<<<384,  256, 0, stream>>>(off_w, wb_off, 393216);
    cvt_k<<<192,  256, 0, stream>>>(aw_w,  wb_aw,  196608);
    cvt_k<<<384,  256, 0, stream>>>(val_w, wb_val, 393216);
    cvt_k<<<384,  256, 0, stream>>>(out_w, wb_out, 393216);
    cvt_k<<<1536, 256, 0, stream>>>(l1_w,  wb_l1,  1572864);
    cvt_k<<<1536, 256, 0, stream>>>(l2_w,  wb_l2,  1572864);

    // 1) transpose inputs + bf16 projections
    for (int i = 0; i < 4; ++i) {
        const int Ml = SS[i] * SS[i];
        tp_k<<<dim3((Ml + 31) / 32, CINS[i] / 32, BB), 256, 0, stream>>>(
            xs[i], xt + XTOFF[i], CINS[i], Ml);
    }
    for (int i = 0; i < 4; ++i) {
        const int Ml = SS[i] * SS[i];
        gemm64<<<dim3((Ml + 63) / 64, 2, BB), 256, 0, stream>>>(
            xt + XTOFF[i], (long)Ml * CINS[i],
            wb_fc[i], nullptr, fcb[i], nullptr, nullptr,
            src + (long)STARTS[i] * DD, (long)LQT * DD, nullptr,
            Ml, DD, CINS[i], 0);
    }
    // 2) group norm (3-phase) -> src f32 + src_bf + q_bf
    gn_part<<<256, 256, 0, stream>>>(src, part);
    gn_fin<<<1, 256, 0, stream>>>(part, stat);
    gn_apply<<<MROWS / 4, 256, 0, stream>>>(src, src_bf, q_bf, stat, gn_g, gn_b, pos);

    // 3) encoder layers
    for (int l = 0; l < 6; ++l) {
        // merged off(256) + aw(128) projection, N=384
        gemm64<<<dim3(383, 3, 1), 256, 0, stream>>>(
            q_bf, 0, wb_off + (long)l * 65536, wb_aw + (long)l * 32768,
            off_b + l * DD, aw_b + l * 128, nullptr,
            awb, 0, off_bf, MROWS, 384, DD, 4);
        gemm64<<<dim3(383, 2, 1), 256, 0, stream>>>(
            src_bf, 0, wb_val + (long)l * 65536, nullptr,
            val_b + l * DD, nullptr, nullptr,
            nullptr, 0, val_bf, MROWS, DD, DD, 3);
        msdeform_k<<<MROWS / 2, 256, 0, stream>>>(val_bf, off_bf, awb, msd_bf);
        gemm64<<<dim3(383, 2, 1), 256, 0, stream>>>(
            msd_bf, 0, wb_out + (long)l * 65536, nullptr,
            out_b + l * DD, nullptr, src,
            tmp, 0, nullptr, MROWS, DD, DD, 2);
        layernorm_k<<<MROWS / 4, 256, 0, stream>>>(
            tmp, ln1_g + l * DD, ln1_b + l * DD, src, src_bf, nullptr, nullptr);
        gemm128<<<dim3(192, 8, 1), 256, 0, stream>>>(
            src_bf, wb_l1 + (long)l * 262144, l1_b + l * DFFN, hid_bf,
            MROWS, DFFN, DD);
        gemm64<<<dim3(383, 2, 1), 256, 0, stream>>>(
            hid_bf, 0, wb_l2 + (long)l * 262144, nullptr,
            l2_b + l * DD, nullptr, src,
            tmp, 0, nullptr, MROWS, DD, DFFN, 2);
        const bool last = (l == 5);
        layernorm_k<<<MROWS / 4, 256, 0, stream>>>(
            tmp, ln2_g + l * DD, ln2_b + l * DD, src, src_bf,
            last ? nullptr : pos, last ? nullptr : q_bf);
    }
    // 4) constant tail outputs
    tail_k<<<1, 32, 0, stream>>>(src + (long)BB * LQT * DD);
}

// Round 5
// 1629.253 us; speedup vs baseline: 4.3076x; 1.0876x over previous
//
#include <hip/hip_runtime.h>
#include <math.h>

#define DD 256
#define DFFN 1024
#define LQT 12240
#define BB 2
#define MROWS (BB * LQT)   // 24480

typedef __attribute__((ext_vector_type(8))) short short8v;
typedef __attribute__((ext_vector_type(4))) float floatx4;

__device__ __forceinline__ unsigned short f2bf(float x) {
    unsigned int u = __builtin_bit_cast(unsigned int, x);
    u = (u + 0x7fffu + ((u >> 16) & 1u)) >> 16;
    return (unsigned short)u;
}
__device__ __forceinline__ float bf2f(unsigned short h) {
    unsigned int u = ((unsigned int)h) << 16;
    return __builtin_bit_cast(float, u);
}

__device__ __forceinline__ void gload16(const unsigned short* g, unsigned short* lds) {
    __builtin_amdgcn_global_load_lds(
        (const __attribute__((address_space(1))) unsigned int*)g,
        (__attribute__((address_space(3))) unsigned int*)lds, 16, 0, 0);
}

__device__ __forceinline__ void level_of(int q, int& lvl, int& start, int& S) {
    if (q < 9216)       { lvl = 0; start = 0;     S = 96; }
    else if (q < 11520) { lvl = 1; start = 9216;  S = 48; }
    else if (q < 12096) { lvl = 2; start = 11520; S = 24; }
    else                { lvl = 3; start = 12096; S = 12; }
}

// ---------------------------------------------------------------------------
// Merged QKV-style projection: grid (383, 5). y<2: off (from q_bf),
// y==2: aw logits f32 (from q_bf), y>=3: val (from src_bf). K=256 unrolled.
// ---------------------------------------------------------------------------
__global__ __launch_bounds__(256)
void gemm_qkv(const unsigned short* __restrict__ Aq,
              const unsigned short* __restrict__ Asr,
              const unsigned short* __restrict__ Woff,
              const unsigned short* __restrict__ Waw,
              const unsigned short* __restrict__ Wval,
              const float* __restrict__ boff, const float* __restrict__ baw,
              const float* __restrict__ bval,
              float* __restrict__ awbo, unsigned short* __restrict__ offo,
              unsigned short* __restrict__ valo)
{
    __shared__ alignas(16) unsigned short As[2][4][64][8];
    __shared__ alignas(16) unsigned short Bs[2][4][128][8];
    const int t = threadIdx.x;
    const int m0 = blockIdx.x * 64;
    const int y = blockIdx.y;
    const unsigned short* A; const unsigned short* Wb; const float* bi;
    int nb, mode;
    if (y < 3) {
        A = Aq;
        if (y < 2) { Wb = Woff; bi = boff; nb = y * 128; mode = 0; }
        else       { Wb = Waw;  bi = baw;  nb = 0;       mode = 1; }
    } else {
        A = Asr; Wb = Wval; bi = bval; nb = (y - 3) * 128; mode = 2;
    }
    const int wv = __builtin_amdgcn_readfirstlane(t >> 6);
    const int lane = t & 63;
    const int wm = wv >> 1, wn = wv & 1;
    const int kb = lane >> 4, lr = lane & 15;

    const int ar = min(m0 + lane, MROWS - 1);
    const unsigned short* gA  = A  + (long)ar * 256 + wv * 8;
    const unsigned short* gB0 = Wb + (long)(nb + lane) * 256 + wv * 8;
    const unsigned short* gB1 = Wb + (long)(nb + 64 + lane) * 256 + wv * 8;

    floatx4 acc[2][4];
    #pragma unroll
    for (int m = 0; m < 2; ++m)
        #pragma unroll
        for (int n = 0; n < 4; ++n)
            acc[m][n] = (floatx4){0.f, 0.f, 0.f, 0.f};

    gload16(gA,  &As[0][wv][0][0]);
    gload16(gB0, &Bs[0][wv][0][0]);
    gload16(gB1, &Bs[0][wv][64][0]);
    gA += 32; gB0 += 32; gB1 += 32;
    __syncthreads();

    #pragma unroll
    for (int kt = 0; kt < 8; ++kt) {
        const int cur = kt & 1;
        if (kt < 7) {
            gload16(gA,  &As[cur ^ 1][wv][0][0]);
            gload16(gB0, &Bs[cur ^ 1][wv][0][0]);
            gload16(gB1, &Bs[cur ^ 1][wv][64][0]);
            gA += 32; gB0 += 32; gB1 += 32;
        }
        short8v av[2], bv[4];
        #pragma unroll
        for (int m = 0; m < 2; ++m)
            av[m] = *(const short8v*)&As[cur][kb][wm * 32 + m * 16 + lr][0];
        #pragma unroll
        for (int n = 0; n < 4; ++n)
            bv[n] = *(const short8v*)&Bs[cur][kb][wn * 64 + n * 16 + lr][0];
        #pragma unroll
        for (int m = 0; m < 2; ++m)
            #pragma unroll
            for (int n = 0; n < 4; ++n)
                acc[m][n] = __builtin_amdgcn_mfma_f32_16x16x32_bf16(
                    av[m], bv[n], acc[m][n], 0, 0, 0);
        __syncthreads();
    }

    const int lh = lane >> 4;
    #pragma unroll
    for (int m = 0; m < 2; ++m) {
        const int row0 = m0 + wm * 32 + m * 16 + lh * 4;
        #pragma unroll
        for (int n = 0; n < 4; ++n) {
            const int col = nb + wn * 64 + n * 16 + lr;
            const float b = bi[col];
            #pragma unroll
            for (int r = 0; r < 4; ++r) {
                const int row = row0 + r;
                if (row >= MROWS) continue;
                const float v = acc[m][n][r] + b;
                if (mode == 0)      offo[(long)row * 256 + col] = f2bf(v);
                else if (mode == 1) awbo[(long)row * 128 + col] = v;
                else                valo[(long)row * 256 + col] = f2bf(v);
            }
        }
    }
}

// ---------------------------------------------------------------------------
// BM=64 x BN=128 bf16 MFMA GEMM, double-buffered global_load_lds staging.
// op: 0 = f32 out (+z batching); 2 = +R f32 out; 3 = bf16 out
// ---------------------------------------------------------------------------
__global__ __launch_bounds__(256)
void gemm64(const unsigned short* __restrict__ A, long aZ,
            const unsigned short* __restrict__ W,
            const float* __restrict__ bias,
            const float* __restrict__ R,
            float* __restrict__ Cf, long cZ, unsigned short* __restrict__ Ch,
            int M, int N, int K, int op)
{
    __shared__ alignas(16) unsigned short As[2][4][64][8];
    __shared__ alignas(16) unsigned short Bs[2][4][128][8];
    const int t = threadIdx.x;
    const int z = blockIdx.z;
    A  += (long)z * aZ;
    if (Cf) Cf += (long)z * cZ;
    const int m0 = blockIdx.x * 64;
    const int n0 = blockIdx.y * 128;
    const int wv = __builtin_amdgcn_readfirstlane(t >> 6);
    const int lane = t & 63;
    const int wm = wv >> 1, wn = wv & 1;
    const int kb = lane >> 4, lr = lane & 15;

    const int ar = min(m0 + lane, M - 1);
    const unsigned short* gA  = A + (long)ar * K + wv * 8;
    const unsigned short* gB0 = W + (long)(n0 + lane) * K + wv * 8;
    const unsigned short* gB1 = W + (long)(n0 + 64 + lane) * K + wv * 8;

    floatx4 acc[2][4];
    #pragma unroll
    for (int m = 0; m < 2; ++m)
        #pragma unroll
        for (int n = 0; n < 4; ++n)
            acc[m][n] = (floatx4){0.f, 0.f, 0.f, 0.f};

    gload16(gA,  &As[0][wv][0][0]);
    gload16(gB0, &Bs[0][wv][0][0]);
    gload16(gB1, &Bs[0][wv][64][0]);
    gA += 32; gB0 += 32; gB1 += 32;
    __syncthreads();

    const int nk = K >> 5;
    for (int kt = 0; kt < nk; ++kt) {
        const int cur = kt & 1;
        if (kt + 1 < nk) {
            gload16(gA,  &As[cur ^ 1][wv][0][0]);
            gload16(gB0, &Bs[cur ^ 1][wv][0][0]);
            gload16(gB1, &Bs[cur ^ 1][wv][64][0]);
            gA += 32; gB0 += 32; gB1 += 32;
        }
        short8v av[2], bv[4];
        #pragma unroll
        for (int m = 0; m < 2; ++m)
            av[m] = *(const short8v*)&As[cur][kb][wm * 32 + m * 16 + lr][0];
        #pragma unroll
        for (int n = 0; n < 4; ++n)
            bv[n] = *(const short8v*)&Bs[cur][kb][wn * 64 + n * 16 + lr][0];
        #pragma unroll
        for (int m = 0; m < 2; ++m)
            #pragma unroll
            for (int n = 0; n < 4; ++n)
                acc[m][n] = __builtin_amdgcn_mfma_f32_16x16x32_bf16(
                    av[m], bv[n], acc[m][n], 0, 0, 0);
        __syncthreads();
    }

    const int lh = lane >> 4;
    #pragma unroll
    for (int m = 0; m < 2; ++m) {
        const int row0 = m0 + wm * 32 + m * 16 + lh * 4;
        #pragma unroll
        for (int n = 0; n < 4; ++n) {
            const int col = n0 + wn * 64 + n * 16 + lr;
            const float b = bias[col];
            #pragma unroll
            for (int r = 0; r < 4; ++r) {
                const int row = row0 + r;
                if (row >= M) continue;
                float v = acc[m][n][r] + b;
                const long o = (long)row * N + col;
                if (op == 0)      Cf[o] = v;
                else if (op == 2) Cf[o] = v + R[o];
                else              Ch[o] = f2bf(v);
            }
        }
    }
}

// ---------------------------------------------------------------------------
// BM=128 x BN=128 variant for FFN1 (relu -> bf16 out), double-buffered
// ---------------------------------------------------------------------------
__global__ __launch_bounds__(256)
void gemm128(const unsigned short* __restrict__ A,
             const unsigned short* __restrict__ W,
             const float* __restrict__ bias, unsigned short* __restrict__ Ch,
             int M, int N, int K)
{
    __shared__ alignas(16) unsigned short As[2][4][128][8];
    __shared__ alignas(16) unsigned short Bs[2][4][128][8];
    const int t = threadIdx.x;
    const int m0 = blockIdx.x * 128;
    const int n0 = blockIdx.y * 128;
    const int wv = __builtin_amdgcn_readfirstlane(t >> 6);
    const int lane = t & 63;
    const int wm = wv >> 1, wn = wv & 1;
    const int kb = lane >> 4, lr = lane & 15;

    const int r0 = min(m0 + lane, M - 1);
    const int r1 = min(m0 + 64 + lane, M - 1);
    const unsigned short* gA0 = A + (long)r0 * K + wv * 8;
    const unsigned short* gA1 = A + (long)r1 * K + wv * 8;
    const unsigned short* gB0 = W + (long)(n0 + lane) * K + wv * 8;
    const unsigned short* gB1 = W + (long)(n0 + 64 + lane) * K + wv * 8;

    floatx4 acc[4][4];
    #pragma unroll
    for (int m = 0; m < 4; ++m)
        #pragma unroll
        for (int n = 0; n < 4; ++n)
            acc[m][n] = (floatx4){0.f, 0.f, 0.f, 0.f};

    gload16(gA0, &As[0][wv][0][0]);
    gload16(gA1, &As[0][wv][64][0]);
    gload16(gB0, &Bs[0][wv][0][0]);
    gload16(gB1, &Bs[0][wv][64][0]);
    gA0 += 32; gA1 += 32; gB0 += 32; gB1 += 32;
    __syncthreads();

    const int nk = K >> 5;
    for (int kt = 0; kt < nk; ++kt) {
        const int cur = kt & 1;
        if (kt + 1 < nk) {
            gload16(gA0, &As[cur ^ 1][wv][0][0]);
            gload16(gA1, &As[cur ^ 1][wv][64][0]);
            gload16(gB0, &Bs[cur ^ 1][wv][0][0]);
            gload16(gB1, &Bs[cur ^ 1][wv][64][0]);
            gA0 += 32; gA1 += 32; gB0 += 32; gB1 += 32;
        }
        short8v av[4], bv[4];
        #pragma unroll
        for (int m = 0; m < 4; ++m)
            av[m] = *(const short8v*)&As[cur][kb][wm * 64 + m * 16 + lr][0];
        #pragma unroll
        for (int n = 0; n < 4; ++n)
            bv[n] = *(const short8v*)&Bs[cur][kb][wn * 64 + n * 16 + lr][0];
        #pragma unroll
        for (int m = 0; m < 4; ++m)
            #pragma unroll
            for (int n = 0; n < 4; ++n)
                acc[m][n] = __builtin_amdgcn_mfma_f32_16x16x32_bf16(
                    av[m], bv[n], acc[m][n], 0, 0, 0);
        __syncthreads();
    }

    const int lh = lane >> 4;
    #pragma unroll
    for (int m = 0; m < 4; ++m) {
        const int row0 = m0 + wm * 64 + m * 16 + lh * 4;
        #pragma unroll
        for (int n = 0; n < 4; ++n) {
            const int col = n0 + wn * 64 + n * 16 + lr;
            const float b = bias[col];
            #pragma unroll
            for (int r = 0; r < 4; ++r) {
                const int row = row0 + r;
                if (row >= M) continue;
                Ch[(long)row * N + col] = f2bf(fmaxf(acc[m][n][r] + b, 0.f));
            }
        }
    }
}

// ---------------------------------------------------------------------------
// transpose (C, Ml) f32 -> (Ml, C) bf16, batch via blockIdx.z
// ---------------------------------------------------------------------------
__global__ __launch_bounds__(256)
void tp_k(const float* __restrict__ x, unsigned short* __restrict__ xt,
          int C, int Ml)
{
    __shared__ float tile[32][33];
    const int m0 = blockIdx.x * 32, c0 = blockIdx.y * 32;
    const int zb = blockIdx.z;
    const float* px = x + (long)zb * C * Ml;
    unsigned short* pxt = xt + (long)zb * Ml * C;
    const int t = threadIdx.x;
    {
        const int cl = t >> 3, m4 = (t & 7) * 4;
        const int gm = m0 + m4;
        if (gm < Ml) {
            const float4 v = *(const float4*)(px + (long)(c0 + cl) * Ml + gm);
            tile[cl][m4 + 0] = v.x; tile[cl][m4 + 1] = v.y;
            tile[cl][m4 + 2] = v.z; tile[cl][m4 + 3] = v.w;
        }
    }
    __syncthreads();
    {
        const int ml = t >> 3, c4 = (t & 7) * 4;
        const int gm = m0 + ml;
        if (gm < Ml) {
            ushort4 o;
            o.x = f2bf(tile[c4 + 0][ml]);
            o.y = f2bf(tile[c4 + 1][ml]);
            o.z = f2bf(tile[c4 + 2][ml]);
            o.w = f2bf(tile[c4 + 3][ml]);
            *(ushort4*)(pxt + (long)gm * C + c0 + c4) = o;
        }
    }
}

// ---------------------------------------------------------------------------
// GroupNorm 3-phase
// ---------------------------------------------------------------------------
__global__ __launch_bounds__(256)
void gn_part(const float* __restrict__ src, float* __restrict__ part)
{
    const int x = blockIdx.x;
    const int b = x >> 7, c = x & 127;
    int lvl, chunk;
    if (c < 96)       { lvl = 0; chunk = c; }
    else if (c < 120) { lvl = 1; chunk = c - 96; }
    else if (c < 126) { lvl = 2; chunk = c - 120; }
    else              { lvl = 3; chunk = c - 126; }
    const int starts[4] = {0, 9216, 11520, 12096};
    const int crows[4]  = {96, 96, 96, 72};
    const int rows = crows[lvl];
    const long base = ((long)b * LQT + starts[lvl] + (long)chunk * rows) * DD;
    const int t = threadIdx.x;
    float s = 0.f, sq = 0.f;
    for (int r = 0; r < rows; ++r) {
        const float v = src[base + (long)r * DD + t];
        s += v; sq += v * v;
    }
    #pragma unroll
    for (int o = 1; o < 8; o <<= 1) {
        s  += __shfl_xor(s, o);
        sq += __shfl_xor(sq, o);
    }
    if ((t & 7) == 0) {
        float* p = part + ((long)x * 32 + (t >> 3)) * 2;
        p[0] = s; p[1] = sq;
    }
}

__global__ void gn_fin(const float* __restrict__ part, float* __restrict__ stat)
{
    const int t = threadIdx.x;
    const int b = t >> 7, rest = t & 127;
    const int lvl = rest >> 5, grp = rest & 31;
    const int cbase[4] = {0, 96, 120, 126};
    const int ccnt[4]  = {96, 24, 6, 2};
    const int Ml[4]    = {9216, 2304, 576, 144};
    float s = 0.f, sq = 0.f;
    for (int i = 0; i < ccnt[lvl]; ++i) {
        const float* p = part + ((long)(b * 128 + cbase[lvl] + i) * 32 + grp) * 2;
        s += p[0]; sq += p[1];
    }
    const float cnt = (float)(Ml[lvl] * 8);
    const float mean = s / cnt;
    const float inv = rsqrtf(sq / cnt - mean * mean + 1e-5f);
    float* o = stat + ((b * 4 + lvl) * 32 + grp) * 2;
    o[0] = mean; o[1] = inv;
}

__global__ __launch_bounds__(256)
void gn_apply(float* __restrict__ src, unsigned short* __restrict__ srch,
              unsigned short* __restrict__ qout,
              const float* __restrict__ stat,
              const float* __restrict__ gg, const float* __restrict__ gb,
              const float* __restrict__ pos)
{
    const int t = threadIdx.x;
    const long row = (long)blockIdx.x * 4 + (t >> 6);
    const int lane = t & 63;
    const int b = row >= LQT;
    const int q = (int)row - b * LQT;
    int lvl, start, S;
    level_of(q, lvl, start, S);
    const float2 ms = *(const float2*)(stat + ((b * 4 + lvl) * 32 + (lane >> 1)) * 2);
    const int col = lane * 4;
    const float4 v  = *(const float4*)(src + row * DD + col);
    const float4 gv = *(const float4*)(gg + lvl * DD + col);
    const float4 bv = *(const float4*)(gb + lvl * DD + col);
    float4 y;
    y.x = (v.x - ms.x) * ms.y * gv.x + bv.x;
    y.y = (v.y - ms.x) * ms.y * gv.y + bv.y;
    y.z = (v.z - ms.x) * ms.y * gv.z + bv.z;
    y.w = (v.w - ms.x) * ms.y * gv.w + bv.w;
    *(float4*)(src + row * DD + col) = y;
    ushort4 hh;
    hh.x = f2bf(y.x); hh.y = f2bf(y.y); hh.z = f2bf(y.z); hh.w = f2bf(y.w);
    *(ushort4*)(srch + row * DD + col) = hh;
    const float4 pv = *(const float4*)(pos + (long)q * DD + col);
    ushort4 qq;
    qq.x = f2bf(y.x + pv.x); qq.y = f2bf(y.y + pv.y);
    qq.z = f2bf(y.z + pv.z); qq.w = f2bf(y.w + pv.w);
    *(ushort4*)(qout + row * DD + col) = qq;
}

__global__ __launch_bounds__(256)
void pos_k(float* __restrict__ pos, const float* __restrict__ lemb)
{
    const int q = blockIdx.x;
    const int d = threadIdx.x;
    int lvl, start, S;
    level_of(q, lvl, start, S);
    const int qi = q - start;
    const int r = qi / S, c = qi % S;
    const float twopi = 6.283185307179586f;
    float e; int dd;
    if (d < 128) { e = (float)(r + 1) / ((float)S + 1e-6f) * twopi; dd = d; }
    else         { e = (float)(c + 1) / ((float)S + 1e-6f) * twopi; dd = d - 128; }
    const float dimt = expf(9.210340371976184f * (float)(dd & ~1) / 128.f);
    const float p = e / dimt;
    const float v = (dd & 1) ? cosf(p) : sinf(p);
    pos[(long)q * DD + d] = v + lemb[lvl * DD + d];
}

// ---------------------------------------------------------------------------
// Deformable attention v5: padded LDS ([5]) to kill 4-way bank conflicts.
// ---------------------------------------------------------------------------
__global__ __launch_bounds__(256)
void msdeform_k(const unsigned short* __restrict__ val,
                const unsigned short* __restrict__ off,
                const float* __restrict__ aw,
                unsigned short* __restrict__ out)
{
    __shared__ int   s_base[2][128][5];
    __shared__ float s_w[2][128][5];
    const int t = threadIdx.x;
    const int j = t >> 7;
    const int tt = t & 127;
    const int bq = blockIdx.x * 2 + j;
    const int b = bq >= LQT;
    const int q = bq - b * LQT;
    int lvl0, start0, S0;
    level_of(q, lvl0, start0, S0);
    const int qi = q - start0;
    {
        const int lv = (tt >> 2) & 3;
        const int SL[4]  = {96, 48, 24, 12};
        const int STL[4] = {0, 9216, 11520, 12096};
        const int S = SL[lv];
        const float refx = ((float)(qi % S0) + 0.5f) / (float)S0;
        const float refy = ((float)(qi / S0) + 0.5f) / (float)S0;
        const unsigned int ou = *(const unsigned int*)(off + (long)bq * 256 + 2 * tt);
        const float x = refx * (float)S - 0.5f + bf2f((unsigned short)(ou & 0xffffu));
        const float y = refy * (float)S - 0.5f + bf2f((unsigned short)(ou >> 16));
        const float logit = aw[(long)bq * 128 + tt];
        float mx = logit;
        #pragma unroll
        for (int s_ = 1; s_ < 16; s_ <<= 1) mx = fmaxf(mx, __shfl_xor(mx, s_));
        const float e = __expf(logit - mx);
        float sum = e;
        #pragma unroll
        for (int s_ = 1; s_ < 16; s_ <<= 1) sum += __shfl_xor(sum, s_);
        const float wat = e / sum;
        const float x0 = floorf(x), y0 = floorf(y);
        const float tx = x - x0, ty = y - y0;
        const int ix = (int)x0, iy = (int)y0;
        #pragma unroll
        for (int c = 0; c < 4; ++c) {
            const int dx = c & 1, dy = c >> 1;
            const int xi = ix + dx, yi = iy + dy;
            const bool ok = (xi >= 0) && (xi < S) && (yi >= 0) && (yi < S);
            const int cx = min(max(xi, 0), S - 1);
            const int cy = min(max(yi, 0), S - 1);
            const float wxy = (dx ? tx : 1.f - tx) * (dy ? ty : 1.f - ty);
            s_base[j][tt][c] = (STL[lv] + cy * S + cx) * 256;
            s_w[j][tt][c] = ok ? wxy * wat : 0.f;
        }
    }
    __syncthreads();
    const int h = tt >> 4, d8 = (tt >> 2) & 3, sub = tt & 3;
    const unsigned short* vb = val + (long)b * (LQT * DD) + h * 32 + d8 * 8;
    float a0 = 0.f, a1 = 0.f, a2 = 0.f, a3 = 0.f;
    float a4 = 0.f, a5 = 0.f, a6 = 0.f, a7 = 0.f;
    #pragma unroll
    for (int i = 0; i < 4; ++i) {
        const int task = h * 16 + i * 4 + sub;
        #pragma unroll
        for (int c = 0; c < 4; ++c) {
            const float wv = s_w[j][task][c];
            const uint4 g = *(const uint4*)(vb + s_base[j][task][c]);
            a0 = fmaf(wv, bf2f((unsigned short)(g.x & 0xffffu)), a0);
            a1 = fmaf(wv, bf2f((unsigned short)(g.x >> 16)), a1);
            a2 = fmaf(wv, bf2f((unsigned short)(g.y & 0xffffu)), a2);
            a3 = fmaf(wv, bf2f((unsigned short)(g.y >> 16)), a3);
            a4 = fmaf(wv, bf2f((unsigned short)(g.z & 0xffffu)), a4);
            a5 = fmaf(wv, bf2f((unsigned short)(g.z >> 16)), a5);
            a6 = fmaf(wv, bf2f((unsigned short)(g.w & 0xffffu)), a6);
            a7 = fmaf(wv, bf2f((unsigned short)(g.w >> 16)), a7);
        }
    }
    #pragma unroll
    for (int o = 1; o < 4; o <<= 1) {
        a0 += __shfl_xor(a0, o); a1 += __shfl_xor(a1, o);
        a2 += __shfl_xor(a2, o); a3 += __shfl_xor(a3, o);
        a4 += __shfl_xor(a4, o); a5 += __shfl_xor(a5, o);
        a6 += __shfl_xor(a6, o); a7 += __shfl_xor(a7, o);
    }
    if (sub == 0) {
        uint4 o;
        o.x = (unsigned)f2bf(a0) | ((unsigned)f2bf(a1) << 16);
        o.y = (unsigned)f2bf(a2) | ((unsigned)f2bf(a3) << 16);
        o.z = (unsigned)f2bf(a4) | ((unsigned)f2bf(a5) << 16);
        o.w = (unsigned)f2bf(a6) | ((unsigned)f2bf(a7) << 16);
        *(uint4*)(out + (long)bq * DD + h * 32 + d8 * 8) = o;
    }
}

// LayerNorm over D=256; 4 rows/block; writes f32 + bf16 (+ optional q=bf16(y+pos))
__global__ __launch_bounds__(256)
void layernorm_k(const float* __restrict__ x, const float* __restrict__ g,
                 const float* __restrict__ b, float* __restrict__ outf,
                 unsigned short* __restrict__ outh,
                 const float* __restrict__ pos, unsigned short* __restrict__ qout)
{
    const int t = threadIdx.x;
    const long row = (long)blockIdx.x * 4 + (t >> 6);
    const int lane = t & 63;
    const float4 v = *(const float4*)(x + row * DD + lane * 4);
    float s  = v.x + v.y + v.z + v.w;
    float sq = v.x * v.x + v.y * v.y + v.z * v.z + v.w * v.w;
    #pragma unroll
    for (int o = 1; o < 64; o <<= 1) {
        s  += __shfl_xor(s, o);
        sq += __shfl_xor(sq, o);
    }
    const float mean = s * (1.f / 256.f);
    const float inv = rsqrtf(sq * (1.f / 256.f) - mean * mean + 1e-5f);
    const float4 gv = *(const float4*)(g + lane * 4);
    const float4 bv = *(const float4*)(b + lane * 4);
    float4 y;
    y.x = (v.x - mean) * inv * gv.x + bv.x;
    y.y = (v.y - mean) * inv * gv.y + bv.y;
    y.z = (v.z - mean) * inv * gv.z + bv.z;
    y.w = (v.w - mean) * inv * gv.w + bv.w;
    *(float4*)(outf + row * DD + lane * 4) = y;
    ushort4 hh;
    hh.x = f2bf(y.x); hh.y = f2bf(y.y); hh.z = f2bf(y.z); hh.w = f2bf(y.w);
    *(ushort4*)(outh + row * DD + lane * 4) = hh;
    if (qout) {
        const int qrow = (int)row - (row >= LQT ? LQT : 0);
        const float4 pv = *(const float4*)(pos + (long)qrow * DD + lane * 4);
        ushort4 qq;
        qq.x = f2bf(y.x + pv.x); qq.y = f2bf(y.y + pv.y);
        qq.z = f2bf(y.z + pv.z); qq.w = f2bf(y.w + pv.w);
        *(ushort4*)(qout + row * DD + lane * 4) = qq;
    }
}

// Fused conversion of ALL weights (10 segments, contiguous dst)
#define WCVT_TOTAL 5177344L
__global__ __launch_bounds__(256)
void wcvt_k(const float* __restrict__ s0, const float* __restrict__ s1,
            const float* __restrict__ s2, const float* __restrict__ s3,
            const float* __restrict__ s4, const float* __restrict__ s5,
            const float* __restrict__ s6, const float* __restrict__ s7,
            const float* __restrict__ s8, const float* __restrict__ s9,
            unsigned short* __restrict__ dst)
{
    const long i = ((long)blockIdx.x * 256 + threadIdx.x) * 4;
    if (i >= WCVT_TOTAL) return;
    const float* sp; long base;
    if (i < 1048576) {
        if (i < 655360) {
            if (i < 65536)       { sp = s0; base = 0; }
            else if (i < 196608) { sp = s1; base = 65536; }
            else if (i < 393216) { sp = s2; base = 196608; }
            else                 { sp = s3; base = 393216; }
        } else                   { sp = s4; base = 655360; }
    } else if (i < 2031616) {
        if (i < 1245184)         { sp = s5; base = 1048576; }
        else if (i < 1638400)    { sp = s6; base = 1245184; }
        else                     { sp = s7; base = 1638400; }
    } else if (i < 3604480)      { sp = s8; base = 2031616; }
    else                         { sp = s9; base = 3604480; }
    const float4 v = *(const float4*)(sp + (i - base));
    ushort4 o;
    o.x = f2bf(v.x); o.y = f2bf(v.y); o.z = f2bf(v.z); o.w = f2bf(v.w);
    *(ushort4*)(dst + i) = o;
}

__global__ void tail_k(float* __restrict__ o)
{
    const float tv[28] = {0.f, 9216.f, 11520.f, 12096.f,
                          96.f, 96.f, 48.f, 48.f, 24.f, 24.f, 12.f, 12.f,
                          1.f, 1.f, 1.f, 1.f, 1.f, 1.f, 1.f, 1.f,
                          1.f, 1.f, 1.f, 1.f, 1.f, 1.f, 1.f, 1.f};
    const int t = threadIdx.x;
    if (t < 28) o[t] = tv[t];
}

extern "C" void kernel_launch(void* const* d_in, const int* in_sizes, int n_in,
                              void* d_out, int out_size, void* d_ws, size_t ws_size,
                              hipStream_t stream)
{
    const float* xs[4]  = {(const float*)d_in[0], (const float*)d_in[3],
                           (const float*)d_in[6], (const float*)d_in[9]};
    const float* fcw[4] = {(const float*)d_in[1], (const float*)d_in[4],
                           (const float*)d_in[7], (const float*)d_in[10]};
    const float* fcb[4] = {(const float*)d_in[2], (const float*)d_in[5],
                           (const float*)d_in[8], (const float*)d_in[11]};
    const float* gn_g = (const float*)d_in[12];
    const float* gn_b = (const float*)d_in[13];
    const float* lemb = (const float*)d_in[14];
    const float* off_w = (const float*)d_in[15];
    const float* off_b = (const float*)d_in[16];
    const float* aw_w  = (const float*)d_in[17];
    const float* aw_b  = (const float*)d_in[18];
    const float* val_w = (const float*)d_in[19];
    const float* val_b = (const float*)d_in[20];
    const float* out_w = (const float*)d_in[21];
    const float* out_b = (const float*)d_in[22];
    const float* ln1_g = (const float*)d_in[23];
    const float* ln1_b = (const float*)d_in[24];
    const float* l1_w  = (const float*)d_in[25];
    const float* l1_b  = (const float*)d_in[26];
    const float* l2_w  = (const float*)d_in[27];
    const float* l2_b  = (const float*)d_in[28];
    const float* ln2_g = (const float*)d_in[29];
    const float* ln2_b = (const float*)d_in[30];

    float* src = (float*)d_out;                 // (B, LQ, D)
    float* ws = (float*)d_ws;
    float* pos = ws;                            // 3,133,440 f32
    float* awb = pos + 3133440;                 // 3,133,440 f32 (aw logits)
    float* tmp = awb + 3133440;                 // 6,266,880 f32 (xt aliased)
    unsigned short* xt = (unsigned short*)tmp;
    unsigned short* q_bf   = (unsigned short*)(tmp + 6266880);
    unsigned short* off_bf = q_bf   + 6266880;
    unsigned short* val_bf = off_bf + 6266880;
    unsigned short* msd_bf = val_bf + 6266880;
    unsigned short* hid_bf = q_bf;              // aliases q/off/val/msd (FFN hidden)
    unsigned short* src_bf = msd_bf + 6266880;
    unsigned short* wb     = src_bf + 6266880;
    unsigned short* wb_fc[4];
    wb_fc[0] = wb;
    wb_fc[1] = wb_fc[0] + 65536;
    wb_fc[2] = wb_fc[1] + 131072;
    wb_fc[3] = wb_fc[2] + 196608;
    unsigned short* wb_off = wb_fc[3] + 262144;
    unsigned short* wb_aw  = wb_off + 393216;
    unsigned short* wb_val = wb_aw  + 196608;
    unsigned short* wb_out = wb_val + 393216;
    unsigned short* wb_l1  = wb_out + 393216;
    unsigned short* wb_l2  = wb_l1  + 1572864;
    float* part = (float*)(wb_l2 + 1572864);    // 16384 f32
    float* stat = part + 16384;                 // 512 f32
    (void)in_sizes; (void)n_in; (void)out_size; (void)ws_size;

    const int CINS[4]   = {256, 512, 768, 1024};
    const int SS[4]     = {96, 48, 24, 12};
    const int STARTS[4] = {0, 9216, 11520, 12096};
    const long XTOFF[4] = {0, 4718592, 7077888, 7962624};

    // 0) positional embedding + all weights -> bf16 (one kernel)
    pos_k<<<LQT, 256, 0, stream>>>(pos, lemb);
    wcvt_k<<<(WCVT_TOTAL / 4 + 255) / 256, 256, 0, stream>>>(
        fcw[0], fcw[1], fcw[2], fcw[3], off_w, aw_w, val_w, out_w, l1_w, l2_w, wb);

    // 1) transpose inputs + bf16 projections
    for (int i = 0; i < 4; ++i) {
        const int Ml = SS[i] * SS[i];
        tp_k<<<dim3((Ml + 31) / 32, CINS[i] / 32, BB), 256, 0, stream>>>(
            xs[i], xt + XTOFF[i], CINS[i], Ml);
    }
    for (int i = 0; i < 4; ++i) {
        const int Ml = SS[i] * SS[i];
        gemm64<<<dim3((Ml + 63) / 64, 2, BB), 256, 0, stream>>>(
            xt + XTOFF[i], (long)Ml * CINS[i],
            wb_fc[i], fcb[i], nullptr,
            src + (long)STARTS[i] * DD, (long)LQT * DD, nullptr,
            Ml, DD, CINS[i], 0);
    }
    // 2) group norm (3-phase) -> src f32 + src_bf + q_bf
    gn_part<<<256, 256, 0, stream>>>(src, part);
    gn_fin<<<1, 256, 0, stream>>>(part, stat);
    gn_apply<<<MROWS / 4, 256, 0, stream>>>(src, src_bf, q_bf, stat, gn_g, gn_b, pos);

    // 3) encoder layers
    for (int l = 0; l < 6; ++l) {
        gemm_qkv<<<dim3(383, 5), 256, 0, stream>>>(
            q_bf, src_bf,
            wb_off + (long)l * 65536, wb_aw + (long)l * 32768,
            wb_val + (long)l * 65536,
            off_b + l * DD, aw_b + l * 128, val_b + l * DD,
            awb, off_bf, val_bf);
        msdeform_k<<<MROWS / 2, 256, 0, stream>>>(val_bf, off_bf, awb, msd_bf);
        gemm64<<<dim3(383, 2), 256, 0, stream>>>(
            msd_bf, 0, wb_out + (long)l * 65536, out_b + l * DD, src,
            tmp, 0, nullptr, MROWS, DD, DD, 2);
        layernorm_k<<<MROWS / 4, 256, 0, stream>>>(
            tmp, ln1_g + l * DD, ln1_b + l * DD, src, src_bf, nullptr, nullptr);
        gemm128<<<dim3(192, 8), 256, 0, stream>>>(
            src_bf, wb_l1 + (long)l * 262144, l1_b + l * DFFN, hid_bf,
            MROWS, DFFN, DD);
        gemm64<<<dim3(383, 2), 256, 0, stream>>>(
            hid_bf, 0, wb_l2 + (long)l * 262144, l2_b + l * DD, src,
            tmp, 0, nullptr, MROWS, DD, DFFN, 2);
        const bool last = (l == 5);
        layernorm_k<<<MROWS / 4, 256, 0, stream>>>(
            tmp, ln2_g + l * DD, ln2_b + l * DD, src, src_bf,
            last ? nullptr : pos, last ? nullptr : q_bf);
    }
    // 4) constant tail outputs
    tail_k<<<1, 32, 0, stream>>>(src + (long)BB * LQT * DD);
}